// Round 1
// baseline (2144.180 us; speedup 1.0000x reference)
//
#include <hip/hip_runtime.h>
#include <cstdint>

#define NVv 40000
#define NCc 300
#define NIi 7000
#define NNn 47300
#define DD 128
#define E1N 500000
#define E2N 500000

// Select the row of the concatenated [visit; ccs; icd] array without materializing it.
__device__ __forceinline__ const float* node_row(const float* __restrict__ v,
                                                 const float* __restrict__ c,
                                                 const float* __restrict__ i, int t) {
    return t < NVv ? v + (size_t)t * DD
         : t < NVv + NCc ? c + (size_t)(t - NVv) * DD
                         : i + (size_t)(t - NVv - NCc) * DD;
}

// L[n] = relu(all_center[n] @ w1^T + b1) @ w2^T + b2   (per-node, 8 nodes per block)
__global__ void node_mlp(const float* __restrict__ vc, const float* __restrict__ cc,
                         const float* __restrict__ ic,
                         const float* __restrict__ w1, const float* __restrict__ b1,
                         const float* __restrict__ w2, const float* __restrict__ b2,
                         float* __restrict__ L) {
    __shared__ float sc[8][DD];
    __shared__ float sh[8][DD];
    const int j = threadIdx.x;            // output dim 0..127
    const int n0 = blockIdx.x * 8;
    #pragma unroll
    for (int i = 0; i < 8; ++i) {
        int n = n0 + i;
        if (n < NNn) sc[i][j] = node_row(vc, cc, ic, n)[j];
    }
    __syncthreads();
    float acc[8];
    float bb = b1[j];
    #pragma unroll
    for (int i = 0; i < 8; ++i) acc[i] = bb;
    for (int k = 0; k < DD; ++k) {
        float w = w1[j * DD + k];
        #pragma unroll
        for (int i = 0; i < 8; ++i) acc[i] = fmaf(w, sc[i][k], acc[i]);
    }
    #pragma unroll
    for (int i = 0; i < 8; ++i) sh[i][j] = fmaxf(acc[i], 0.f);
    __syncthreads();
    bb = b2[j];
    #pragma unroll
    for (int i = 0; i < 8; ++i) acc[i] = bb;
    for (int k = 0; k < DD; ++k) {
        float w = w2[j * DD + k];
        #pragma unroll
        for (int i = 0; i < 8; ++i) acc[i] = fmaf(w, sh[i][k], acc[i]);
    }
    #pragma unroll
    for (int i = 0; i < 8; ++i) {
        int n = n0 + i;
        if (n < NNn) L[(size_t)n * DD + j] = acc[i];
    }
}

// Segment softmax accumulation (shift-free: exp(logit) directly — logits bounded ~|4|).
// 32 threads per edge, float4 per thread. num lives in out0.
__global__ void edge_accum(const int* __restrict__ g,
                           const float* __restrict__ L,
                           const float* __restrict__ vc, const float* __restrict__ cc,
                           const float* __restrict__ ic,
                           float* __restrict__ num, float* __restrict__ den) {
    int gid = blockIdx.x * blockDim.x + threadIdx.x;
    int e = gid >> 5;
    if (e >= E1N) return;
    int h = g[e];
    if (h >= NVv) return;                 // only segments < NV survive the [:NV] slice
    int t = g[E1N + e];
    int q = (gid & 31) << 2;
    const float4 lv = *(const float4*)(L + (size_t)t * DD + q);
    const float4 cv = *(const float4*)(node_row(vc, cc, ic, t) + q);
    float w0 = __expf(lv.x), w1 = __expf(lv.y), w2 = __expf(lv.z), w3 = __expf(lv.w);
    float* dp = den + (size_t)h * DD + q;
    float* np = num + (size_t)h * DD + q;
    atomicAdd(dp + 0, w0); atomicAdd(np + 0, w0 * cv.x);
    atomicAdd(dp + 1, w1); atomicAdd(np + 1, w1 * cv.y);
    atomicAdd(dp + 2, w2); atomicAdd(np + 2, w2 * cv.z);
    atomicAdd(dp + 3, w3); atomicAdd(np + 3, w3 * cv.w);
}

// out0 = l2norm(num/den) per node; one 64-lane wave per node, 2 dims/lane.
__global__ void finalize(float* __restrict__ out0, const float* __restrict__ den) {
    int lane = threadIdx.x & 63;
    int wid = blockIdx.x * (blockDim.x >> 6) + (threadIdx.x >> 6);
    if (wid >= NVv) return;
    size_t base = (size_t)wid * DD;
    float d0 = den[base + lane], d1 = den[base + 64 + lane];
    float n0 = out0[base + lane], n1 = out0[base + 64 + lane];
    float v0 = d0 > 0.f ? n0 / d0 : 0.f;
    float v1 = d1 > 0.f ? n1 / d1 : 0.f;
    float ss = v0 * v0 + v1 * v1;
    #pragma unroll
    for (int off = 32; off; off >>= 1) ss += __shfl_xor(ss, off);
    float inv = 1.f / fmaxf(sqrtf(ss), 1e-12f);
    out0[base + lane] = v0 * inv;
    out0[base + 64 + lane] = v1 * inv;
}

// Fused 5-way offset segment-max: {g1: h<NV && t>=NV} ∪ {g2: h<NV}, val = relu(offset[t]).
// Positive-float bits are monotone as unsigned → atomicMax(u32), init 0.
__global__ void offset_max(const int* __restrict__ g1, const int* __restrict__ g2,
                           const float* __restrict__ vo, const float* __restrict__ co,
                           const float* __restrict__ io,
                           unsigned* __restrict__ out1) {
    int gid = blockIdx.x * blockDim.x + threadIdx.x;
    int e = gid >> 5;
    int q = (gid & 31) << 2;
    int h, t;
    if (e < E1N) {
        h = g1[e]; t = g1[E1N + e];
        if (h >= NVv || t < NVv) return;
    } else {
        int e2 = e - E1N;
        if (e2 >= E2N) return;
        h = g2[e2]; t = g2[E2N + e2];
        if (h >= NVv) return;
    }
    const float4 v = *(const float4*)(node_row(vo, co, io, t) + q);
    unsigned* o = out1 + (size_t)h * DD + q;
    if (v.x > 0.f) atomicMax(o + 0, __float_as_uint(v.x));
    if (v.y > 0.f) atomicMax(o + 1, __float_as_uint(v.y));
    if (v.z > 0.f) atomicMax(o + 2, __float_as_uint(v.z));
    if (v.w > 0.f) atomicMax(o + 3, __float_as_uint(v.w));
}

extern "C" void kernel_launch(void* const* d_in, const int* in_sizes, int n_in,
                              void* d_out, int out_size, void* d_ws, size_t ws_size,
                              hipStream_t stream) {
    const float* vc  = (const float*)d_in[0];
    const float* vo  = (const float*)d_in[1];
    const float* cc  = (const float*)d_in[2];
    const float* co  = (const float*)d_in[3];
    const float* ic  = (const float*)d_in[4];
    const float* io  = (const float*)d_in[5];
    // d_in[6] visit_time, d_in[11..14] tw1/tb1/tw2/tb2: dead (lam == 1.0)
    const float* aw1 = (const float*)d_in[7];
    const float* ab1 = (const float*)d_in[8];
    const float* aw2 = (const float*)d_in[9];
    const float* ab2 = (const float*)d_in[10];
    const int*   g1  = (const int*)d_in[15];
    const int*   g2  = (const int*)d_in[16];

    float* out0 = (float*)d_out;                    // num accumulator, then final emb
    float* out1 = out0 + (size_t)NVv * DD;          // offset output
    float* L    = (float*)d_ws;                     // [NN,128] node logits
    float* den  = L + (size_t)NNn * DD;             // [NV,128] softmax denominators

    // zero accumulators every call (harness poisons once, never re-poisons)
    hipMemsetAsync(d_out, 0, (size_t)out_size * sizeof(float), stream);
    hipMemsetAsync(den, 0, (size_t)NVv * DD * sizeof(float), stream);

    node_mlp<<<(NNn + 7) / 8, 128, 0, stream>>>(vc, cc, ic, aw1, ab1, aw2, ab2, L);
    edge_accum<<<(E1N * 32) / 256, 256, 0, stream>>>(g1, L, vc, cc, ic, out0, den);
    finalize<<<(NVv + 3) / 4, 256, 0, stream>>>(out0, den);
    offset_max<<<((E1N + E2N) * 32) / 256, 256, 0, stream>>>(g1, g2, vo, co, io,
                                                             (unsigned*)out1);
}

// Round 2
// 421.385 us; speedup vs baseline: 5.0884x; 5.0884x over previous
//
#include <hip/hip_runtime.h>
#include <cstdint>

#define NVv 40000
#define NCc 300
#define NIi 7000
#define NNn 47300
#define DD 128
#define E1N 500000
#define E2N 500000

// Row of the virtual concatenated [visit; ccs; icd] array.
__device__ __forceinline__ const float* node_row(const float* __restrict__ v,
                                                 const float* __restrict__ c,
                                                 const float* __restrict__ i, int t) {
    return t < NVv ? v + (size_t)t * DD
         : t < NVv + NCc ? c + (size_t)(t - NVv) * DD
                         : i + (size_t)(t - NVv - NCc) * DD;
}

// EL[n] = exp( relu(all_center[n] @ w1^T + b1) @ w2^T + b2 )   (8 nodes per block)
__global__ void node_mlp(const float* __restrict__ vc, const float* __restrict__ cc,
                         const float* __restrict__ ic,
                         const float* __restrict__ w1, const float* __restrict__ b1,
                         const float* __restrict__ w2, const float* __restrict__ b2,
                         float* __restrict__ EL) {
    __shared__ float sc[8][DD];
    __shared__ float sh[8][DD];
    const int j = threadIdx.x;            // output dim 0..127
    const int n0 = blockIdx.x * 8;
    #pragma unroll
    for (int i = 0; i < 8; ++i) {
        int n = n0 + i;
        if (n < NNn) sc[i][j] = node_row(vc, cc, ic, n)[j];
    }
    __syncthreads();
    float acc[8];
    float bb = b1[j];
    #pragma unroll
    for (int i = 0; i < 8; ++i) acc[i] = bb;
    for (int k = 0; k < DD; ++k) {
        float w = w1[j * DD + k];
        #pragma unroll
        for (int i = 0; i < 8; ++i) acc[i] = fmaf(w, sc[i][k], acc[i]);
    }
    #pragma unroll
    for (int i = 0; i < 8; ++i) sh[i][j] = fmaxf(acc[i], 0.f);
    __syncthreads();
    bb = b2[j];
    #pragma unroll
    for (int i = 0; i < 8; ++i) acc[i] = bb;
    for (int k = 0; k < DD; ++k) {
        float w = w2[j * DD + k];
        #pragma unroll
        for (int i = 0; i < 8; ++i) acc[i] = fmaf(w, sh[i][k], acc[i]);
    }
    #pragma unroll
    for (int i = 0; i < 8; ++i) {
        int n = n0 + i;
        if (n < NNn) EL[(size_t)n * DD + j] = __expf(acc[i]);  // shift-free softmax weight
    }
}

// Histogram of edges per head node (h < NV only), both graphs in one grid.
__global__ void hist(const int* __restrict__ g1, const int* __restrict__ g2,
                     int* __restrict__ cnt1, int* __restrict__ cnt2) {
    int gid = blockIdx.x * blockDim.x + threadIdx.x;
    if (gid < E1N) {
        int h = g1[gid];
        if (h < NVv) atomicAdd(cnt1 + h, 1);
    } else if (gid < E1N + E2N) {
        int h = g2[gid - E1N];
        if (h < NVv) atomicAdd(cnt2 + h, 1);
    }
}

// Single-block exclusive scan of cnt[0..NV) -> base[0..NV], cur copy.
__global__ __launch_bounds__(1024) void exscan(const int* __restrict__ cnt,
                                               int* __restrict__ basep,
                                               int* __restrict__ cur) {
    __shared__ int wsum[16];
    __shared__ int carry;
    const int tid = threadIdx.x;
    const int lane = tid & 63, wv = tid >> 6;
    if (tid == 0) carry = 0;
    __syncthreads();
    for (int start = 0; start < NVv; start += 1024) {
        int i = start + tid;
        int v = (i < NVv) ? cnt[i] : 0;
        int incl = v;
        #pragma unroll
        for (int off = 1; off < 64; off <<= 1) {
            int o = __shfl_up(incl, off);
            if (lane >= off) incl += o;
        }
        if (lane == 63) wsum[wv] = incl;
        __syncthreads();
        int wpre = 0;
        for (int w = 0; w < wv; ++w) wpre += wsum[w];
        int excl = carry + wpre + (incl - v);
        if (i < NVv) { basep[i] = excl; cur[i] = excl; }
        int tot = excl + v;
        __syncthreads();
        if (tid == 1023) carry = tot;   // = carry + chunk total
        __syncthreads();
    }
    if (tid == 0) basep[NVv] = carry;
}

// Scatter tail indices into CSR slots.
__global__ void scatter(const int* __restrict__ g1, const int* __restrict__ g2,
                        int* __restrict__ cur1, int* __restrict__ cur2,
                        int* __restrict__ csr1, int* __restrict__ csr2) {
    int gid = blockIdx.x * blockDim.x + threadIdx.x;
    if (gid < E1N) {
        int h = g1[gid];
        if (h < NVv) csr1[atomicAdd(cur1 + h, 1)] = g1[E1N + gid];
    } else if (gid < E1N + E2N) {
        int e = gid - E1N;
        int h = g2[e];
        if (h < NVv) csr2[atomicAdd(cur2 + h, 1)] = g2[E2N + e];
    }
}

// One wave per segment: register-accumulated segment softmax + l2norm, no atomics.
__global__ void seg_softmax(const int* __restrict__ base, const int* __restrict__ csr,
                            const float* __restrict__ EL,
                            const float* __restrict__ vc, const float* __restrict__ cc,
                            const float* __restrict__ ic,
                            float* __restrict__ out0) {
    int seg = blockIdx.x * (blockDim.x >> 6) + (threadIdx.x >> 6);
    if (seg >= NVv) return;
    int lane = threadIdx.x & 63;
    int s = base[seg], e = base[seg + 1];
    float n0 = 0.f, n1 = 0.f, d0 = 0.f, d1 = 0.f;
    for (int k = s; k < e; ++k) {
        int t = csr[k];
        const float* el = EL + (size_t)t * DD;
        const float* cr = node_row(vc, cc, ic, t);
        float w0 = el[lane], w1 = el[lane + 64];
        d0 += w0;
        d1 += w1;
        n0 = fmaf(w0, cr[lane], n0);
        n1 = fmaf(w1, cr[lane + 64], n1);
    }
    float v0 = d0 > 0.f ? n0 / d0 : 0.f;
    float v1 = d1 > 0.f ? n1 / d1 : 0.f;
    float ss = v0 * v0 + v1 * v1;
    #pragma unroll
    for (int off = 32; off; off >>= 1) ss += __shfl_xor(ss, off);
    float inv = 1.f / fmaxf(sqrtf(ss), 1e-12f);
    size_t b = (size_t)seg * DD;
    out0[b + lane] = v0 * inv;
    out0[b + 64 + lane] = v1 * inv;
}

// One wave per segment: fused 5-way relu/segment-max (g1 edges need t>=NV; g2 all).
__global__ void seg_offmax(const int* __restrict__ base1, const int* __restrict__ csr1,
                           const int* __restrict__ base2, const int* __restrict__ csr2,
                           const float* __restrict__ vo, const float* __restrict__ co,
                           const float* __restrict__ io,
                           float* __restrict__ out1) {
    int seg = blockIdx.x * (blockDim.x >> 6) + (threadIdx.x >> 6);
    if (seg >= NVv) return;
    int lane = threadIdx.x & 63;
    float m0 = 0.f, m1 = 0.f;                       // init 0 == relu + empty default
    int s = base1[seg], e = base1[seg + 1];
    for (int k = s; k < e; ++k) {
        int t = csr1[k];
        if (t < NVv) continue;                      // g1 mask: t >= NV
        const float* r = node_row(vo, co, io, t);
        m0 = fmaxf(m0, r[lane]);
        m1 = fmaxf(m1, r[lane + 64]);
    }
    s = base2[seg]; e = base2[seg + 1];
    for (int k = s; k < e; ++k) {
        int t = csr2[k];
        const float* r = node_row(vo, co, io, t);
        m0 = fmaxf(m0, r[lane]);
        m1 = fmaxf(m1, r[lane + 64]);
    }
    size_t b = (size_t)seg * DD;
    out1[b + lane] = m0;
    out1[b + 64 + lane] = m1;
}

extern "C" void kernel_launch(void* const* d_in, const int* in_sizes, int n_in,
                              void* d_out, int out_size, void* d_ws, size_t ws_size,
                              hipStream_t stream) {
    const float* vc  = (const float*)d_in[0];
    const float* vo  = (const float*)d_in[1];
    const float* cc  = (const float*)d_in[2];
    const float* co  = (const float*)d_in[3];
    const float* ic  = (const float*)d_in[4];
    const float* io  = (const float*)d_in[5];
    // d_in[6] visit_time, d_in[11..14] time-net params: dead (lam == 1.0)
    const float* aw1 = (const float*)d_in[7];
    const float* ab1 = (const float*)d_in[8];
    const float* aw2 = (const float*)d_in[9];
    const float* ab2 = (const float*)d_in[10];
    const int*   g1  = (const int*)d_in[15];
    const int*   g2  = (const int*)d_in[16];

    float* out0 = (float*)d_out;                    // [NV,128] final emb
    float* out1 = out0 + (size_t)NVv * DD;          // [NV,128] final offset

    float* EL   = (float*)d_ws;                     // [NN,128] exp(logits)
    int* cnt1   = (int*)(EL + (size_t)NNn * DD);
    int* cnt2   = cnt1 + NVv;
    int* base1  = cnt2 + NVv;                       // NV+1
    int* cur1   = base1 + NVv + 1;
    int* base2  = cur1 + NVv;                       // NV+1
    int* cur2   = base2 + NVv + 1;
    int* csr1   = cur2 + NVv;                       // E1N
    int* csr2   = csr1 + E1N;                       // E2N

    hipMemsetAsync(cnt1, 0, 2 * NVv * sizeof(int), stream);  // cnt1+cnt2 contiguous

    node_mlp<<<(NNn + 7) / 8, 128, 0, stream>>>(vc, cc, ic, aw1, ab1, aw2, ab2, EL);

    int eblocks = (E1N + E2N + 255) / 256;
    hist<<<eblocks, 256, 0, stream>>>(g1, g2, cnt1, cnt2);
    exscan<<<1, 1024, 0, stream>>>(cnt1, base1, cur1);
    exscan<<<1, 1024, 0, stream>>>(cnt2, base2, cur2);
    scatter<<<eblocks, 256, 0, stream>>>(g1, g2, cur1, cur2, csr1, csr2);

    seg_softmax<<<(NVv + 3) / 4, 256, 0, stream>>>(base1, csr1, EL, vc, cc, ic, out0);
    seg_offmax<<<(NVv + 3) / 4, 256, 0, stream>>>(base1, csr1, base2, csr2,
                                                  vo, co, io, out1);
}

// Round 3
// 246.475 us; speedup vs baseline: 8.6994x; 1.7096x over previous
//
#include <hip/hip_runtime.h>
#include <cstdint>

#define NVv 40000
#define NCc 300
#define NIi 7000
#define NNn 47300
#define DD 128
#define E1N 500000
#define E2N 500000

#define SCAN_N (2 * NVv)                     // joint count array (g1 | g2)
#define SCAN_NB ((SCAN_N + 1023) / 1024)     // 79 partial blocks

typedef __attribute__((ext_vector_type(8))) short short8v;
typedef __attribute__((ext_vector_type(4))) float f32x4;

__device__ __forceinline__ short f2bf(float f) {   // RNE f32->bf16
    unsigned u = __float_as_uint(f);
    u += 0x7FFF + ((u >> 16) & 1);
    return (short)(u >> 16);
}

// Row of the virtual concatenated [visit; ccs; icd] array.
__device__ __forceinline__ const float* node_row(const float* __restrict__ v,
                                                 const float* __restrict__ c,
                                                 const float* __restrict__ i, int t) {
    return t < NVv ? v + (size_t)t * DD
         : t < NVv + NCc ? c + (size_t)(t - NVv) * DD
                         : i + (size_t)(t - NVv - NCc) * DD;
}

// EL[n] = exp( relu(center[n] @ w1^T + b1) @ w2^T + b2 ), bf16 MFMA.
// 64 nodes/block, 4 waves x 16 rows. Weights staged to LDS bf16, rows padded to
// 136 (stride 272 B == 4 banks mod 32 -> conflict-free ds_read_b128).
__global__ __launch_bounds__(256) void node_mlp(
        const float* __restrict__ vc, const float* __restrict__ cc,
        const float* __restrict__ ic,
        const float* __restrict__ w1, const float* __restrict__ b1,
        const float* __restrict__ w2, const float* __restrict__ b2,
        float* __restrict__ EL) {
    __shared__ short wbuf[128][136];
    __shared__ short hbuf[64][136];
    const int tid = threadIdx.x;
    const int lane = tid & 63, wv = tid >> 6;
    const int n0 = blockIdx.x * 64 + wv * 16;
    const int colw = lane & 15;              // col within a 16-tile
    const int k0 = (lane >> 4) * 8;          // k sub-offset for A/B frags

    // stage w1 -> bf16 LDS (row-major [j][k])
    for (int idx = tid * 4; idx < DD * DD; idx += 1024) {
        float4 v = *(const float4*)(w1 + idx);
        short* p = &wbuf[idx >> 7][idx & 127];
        p[0] = f2bf(v.x); p[1] = f2bf(v.y); p[2] = f2bf(v.z); p[3] = f2bf(v.w);
    }

    // A frags (layer 1) straight from global: row = n0 + (lane&15)
    int arow = n0 + colw; if (arow >= NNn) arow = NNn - 1;
    const float* ar = node_row(vc, cc, ic, arow);
    short8v a[4];
    #pragma unroll
    for (int kf = 0; kf < 4; ++kf) {
        const float* p = ar + kf * 32 + k0;
        float4 x = *(const float4*)p;
        float4 y = *(const float4*)(p + 4);
        short8v t;
        t[0] = f2bf(x.x); t[1] = f2bf(x.y); t[2] = f2bf(x.z); t[3] = f2bf(x.w);
        t[4] = f2bf(y.x); t[5] = f2bf(y.y); t[6] = f2bf(y.z); t[7] = f2bf(y.w);
        a[kf] = t;
    }
    __syncthreads();

    // layer 1: h = relu(A @ W1^T + b1) -> hbuf (own wave's 16 rows)
    #pragma unroll
    for (int jt = 0; jt < 8; ++jt) {
        int j = jt * 16 + colw;
        float bb = b1[j];
        f32x4 acc = {bb, bb, bb, bb};
        #pragma unroll
        for (int kf = 0; kf < 4; ++kf) {
            short8v b = *(short8v*)&wbuf[j][kf * 32 + k0];
            acc = __builtin_amdgcn_mfma_f32_16x16x32_bf16(a[kf], b, acc, 0, 0, 0);
        }
        #pragma unroll
        for (int r = 0; r < 4; ++r)
            hbuf[wv * 16 + (lane >> 4) * 4 + r][j] = f2bf(fmaxf(acc[r], 0.f));
    }
    __syncthreads();                         // all waves done reading wbuf(w1)

    // A frags (layer 2) from own hbuf rows
    short8v a2[4];
    #pragma unroll
    for (int kf = 0; kf < 4; ++kf)
        a2[kf] = *(short8v*)&hbuf[wv * 16 + colw][kf * 32 + k0];

    // stage w2 over wbuf
    for (int idx = tid * 4; idx < DD * DD; idx += 1024) {
        float4 v = *(const float4*)(w2 + idx);
        short* p = &wbuf[idx >> 7][idx & 127];
        p[0] = f2bf(v.x); p[1] = f2bf(v.y); p[2] = f2bf(v.z); p[3] = f2bf(v.w);
    }
    __syncthreads();

    // layer 2 + exp -> EL
    #pragma unroll
    for (int jt = 0; jt < 8; ++jt) {
        int j = jt * 16 + colw;
        float bb = b2[j];
        f32x4 acc = {bb, bb, bb, bb};
        #pragma unroll
        for (int kf = 0; kf < 4; ++kf) {
            short8v b = *(short8v*)&wbuf[j][kf * 32 + k0];
            acc = __builtin_amdgcn_mfma_f32_16x16x32_bf16(a2[kf], b, acc, 0, 0, 0);
        }
        #pragma unroll
        for (int r = 0; r < 4; ++r) {
            int n = n0 + (lane >> 4) * 4 + r;
            if (n < NNn) EL[(size_t)n * DD + j] = __expf(acc[r]);
        }
    }
}

// ---- CSR build: joint histogram (g1 -> seg h, g2 -> seg NV+h) ----
__global__ void hist(const int* __restrict__ g1, const int* __restrict__ g2,
                     int* __restrict__ cnt) {
    int gid = blockIdx.x * blockDim.x + threadIdx.x;
    if (gid < E1N) {
        int h = g1[gid];
        if (h < NVv) atomicAdd(cnt + h, 1);
    } else if (gid < E1N + E2N) {
        int h = g2[gid - E1N];
        if (h < NVv) atomicAdd(cnt + NVv + h, 1);
    }
}

__global__ __launch_bounds__(1024) void scan_partial(const int* __restrict__ cnt,
                                                     int* __restrict__ bsum) {
    __shared__ int ws[16];
    int tid = threadIdx.x, lane = tid & 63, wvi = tid >> 6;
    int i = blockIdx.x * 1024 + tid;
    int v = (i < SCAN_N) ? cnt[i] : 0;
    #pragma unroll
    for (int off = 32; off; off >>= 1) v += __shfl_xor(v, off);
    if (lane == 0) ws[wvi] = v;
    __syncthreads();
    if (tid == 0) {
        int s = 0;
        #pragma unroll
        for (int w = 0; w < 16; ++w) s += ws[w];
        bsum[blockIdx.x] = s;
    }
}

__global__ __launch_bounds__(128) void scan_mid(const int* __restrict__ bsum,
                                                int* __restrict__ bof,
                                                int* __restrict__ base) {
    __shared__ int wsum0;
    int tid = threadIdx.x, lane = tid & 63, wvi = tid >> 6;
    int v = (tid < SCAN_NB) ? bsum[tid] : 0;
    int incl = v;
    #pragma unroll
    for (int off = 1; off < 64; off <<= 1) {
        int o = __shfl_up(incl, off);
        if (lane >= off) incl += o;
    }
    if (lane == 63 && wvi == 0) wsum0 = incl;
    __syncthreads();
    int excl = incl - v + (wvi ? wsum0 : 0);
    if (tid < SCAN_NB) bof[tid] = excl;
    if (tid == SCAN_NB - 1) base[SCAN_N] = excl + v;   // grand total
}

__global__ __launch_bounds__(1024) void scan_final(const int* __restrict__ cnt,
                                                   const int* __restrict__ bof,
                                                   int* __restrict__ base,
                                                   int* __restrict__ cur) {
    __shared__ int ws[16];
    int tid = threadIdx.x, lane = tid & 63, wvi = tid >> 6;
    int i = blockIdx.x * 1024 + tid;
    int v = (i < SCAN_N) ? cnt[i] : 0;
    int incl = v;
    #pragma unroll
    for (int off = 1; off < 64; off <<= 1) {
        int o = __shfl_up(incl, off);
        if (lane >= off) incl += o;
    }
    if (lane == 63) ws[wvi] = incl;
    __syncthreads();
    int wpre = 0;
    for (int w = 0; w < wvi; ++w) wpre += ws[w];
    int excl = bof[blockIdx.x] + wpre + incl - v;
    if (i < SCAN_N) { base[i] = excl; cur[i] = excl; }
}

__global__ void scatter(const int* __restrict__ g1, const int* __restrict__ g2,
                        int* __restrict__ cur, int* __restrict__ csr) {
    int gid = blockIdx.x * blockDim.x + threadIdx.x;
    if (gid < E1N) {
        int h = g1[gid];
        if (h < NVv) csr[atomicAdd(cur + h, 1)] = g1[E1N + gid];
    } else if (gid < E1N + E2N) {
        int e = gid - E1N;
        int h = g2[e];
        if (h < NVv) csr[atomicAdd(cur + NVv + h, 1)] = g2[E2N + e];
    }
}

// One wave per segment: register segment softmax + l2norm, no atomics.
__global__ void seg_softmax(const int* __restrict__ base, const int* __restrict__ csr,
                            const float* __restrict__ EL,
                            const float* __restrict__ vc, const float* __restrict__ cc,
                            const float* __restrict__ ic,
                            float* __restrict__ out0) {
    int seg = blockIdx.x * (blockDim.x >> 6) + (threadIdx.x >> 6);
    if (seg >= NVv) return;
    int lane = threadIdx.x & 63;
    int s = base[seg], e = base[seg + 1];
    float n0 = 0.f, n1 = 0.f, d0 = 0.f, d1 = 0.f;
    for (int k = s; k < e; ++k) {
        int t = csr[k];
        const float* el = EL + (size_t)t * DD;
        const float* cr = node_row(vc, cc, ic, t);
        float w0 = el[lane], w1 = el[lane + 64];
        d0 += w0;
        d1 += w1;
        n0 = fmaf(w0, cr[lane], n0);
        n1 = fmaf(w1, cr[lane + 64], n1);
    }
    float v0 = d0 > 0.f ? n0 / d0 : 0.f;
    float v1 = d1 > 0.f ? n1 / d1 : 0.f;
    float ss = v0 * v0 + v1 * v1;
    #pragma unroll
    for (int off = 32; off; off >>= 1) ss += __shfl_xor(ss, off);
    float inv = 1.f / fmaxf(sqrtf(ss), 1e-12f);
    size_t b = (size_t)seg * DD;
    out0[b + lane] = v0 * inv;
    out0[b + 64 + lane] = v1 * inv;
}

// One wave per segment: fused 5-way relu/segment-max (g1 needs t>=NV; g2 all).
__global__ void seg_offmax(const int* __restrict__ base, const int* __restrict__ csr,
                           const float* __restrict__ vo, const float* __restrict__ co,
                           const float* __restrict__ io,
                           float* __restrict__ out1) {
    int seg = blockIdx.x * (blockDim.x >> 6) + (threadIdx.x >> 6);
    if (seg >= NVv) return;
    int lane = threadIdx.x & 63;
    float m0 = 0.f, m1 = 0.f;                // 0 == relu floor + empty default
    int s = base[seg], e = base[seg + 1];
    for (int k = s; k < e; ++k) {
        int t = csr[k];
        if (t < NVv) continue;               // g1 mask: t >= NV
        const float* r = node_row(vo, co, io, t);
        m0 = fmaxf(m0, r[lane]);
        m1 = fmaxf(m1, r[lane + 64]);
    }
    s = base[NVv + seg]; e = base[NVv + seg + 1];
    for (int k = s; k < e; ++k) {
        int t = csr[k];
        const float* r = node_row(vo, co, io, t);
        m0 = fmaxf(m0, r[lane]);
        m1 = fmaxf(m1, r[lane + 64]);
    }
    size_t b = (size_t)seg * DD;
    out1[b + lane] = m0;
    out1[b + 64 + lane] = m1;
}

extern "C" void kernel_launch(void* const* d_in, const int* in_sizes, int n_in,
                              void* d_out, int out_size, void* d_ws, size_t ws_size,
                              hipStream_t stream) {
    const float* vc  = (const float*)d_in[0];
    const float* vo  = (const float*)d_in[1];
    const float* cc  = (const float*)d_in[2];
    const float* co  = (const float*)d_in[3];
    const float* ic  = (const float*)d_in[4];
    const float* io  = (const float*)d_in[5];
    // d_in[6] visit_time, d_in[11..14] time-net params: dead (lam == 1.0)
    const float* aw1 = (const float*)d_in[7];
    const float* ab1 = (const float*)d_in[8];
    const float* aw2 = (const float*)d_in[9];
    const float* ab2 = (const float*)d_in[10];
    const int*   g1  = (const int*)d_in[15];
    const int*   g2  = (const int*)d_in[16];

    float* out0 = (float*)d_out;                    // [NV,128] final emb
    float* out1 = out0 + (size_t)NVv * DD;          // [NV,128] final offset

    float* EL  = (float*)d_ws;                      // [NN,128] exp(logits)
    int* cnt   = (int*)(EL + (size_t)NNn * DD);     // SCAN_N
    int* base  = cnt + SCAN_N;                      // SCAN_N + 1
    int* cur   = base + SCAN_N + 1;                 // SCAN_N
    int* bsum  = cur + SCAN_N;                      // 128
    int* bof   = bsum + 128;                        // 128
    int* csr   = bof + 128;                         // E1N + E2N

    hipMemsetAsync(cnt, 0, SCAN_N * sizeof(int), stream);

    node_mlp<<<(NNn + 63) / 64, 256, 0, stream>>>(vc, cc, ic, aw1, ab1, aw2, ab2, EL);

    int eblocks = (E1N + E2N + 255) / 256;
    hist<<<eblocks, 256, 0, stream>>>(g1, g2, cnt);
    scan_partial<<<SCAN_NB, 1024, 0, stream>>>(cnt, bsum);
    scan_mid<<<1, 128, 0, stream>>>(bsum, bof, base);
    scan_final<<<SCAN_NB, 1024, 0, stream>>>(cnt, bof, base, cur);
    scatter<<<eblocks, 256, 0, stream>>>(g1, g2, cur, csr);

    seg_softmax<<<(NVv + 3) / 4, 256, 0, stream>>>(base, csr, EL, vc, cc, ic, out0);
    seg_offmax<<<(NVv + 3) / 4, 256, 0, stream>>>(base, csr, vo, co, io, out1);
}

// Round 4
// 214.027 us; speedup vs baseline: 10.0183x; 1.1516x over previous
//
#include <hip/hip_runtime.h>
#include <cstdint>

#define NVv 40000
#define NCc 300
#define NIi 7000
#define NNn 47300
#define DD 128
#define E1N 500000
#define E2N 500000

#define SCAN_N (2 * NVv)                     // joint count array (g1 | g2)
#define SCAN_NB ((SCAN_N + 1023) / 1024)     // 79 partial blocks

typedef __attribute__((ext_vector_type(8))) short short8v;
typedef __attribute__((ext_vector_type(4))) short short4v;
typedef __attribute__((ext_vector_type(4))) float f32x4;

__device__ __forceinline__ short f2bf(float f) {   // RNE f32->bf16
    unsigned u = __float_as_uint(f);
    u += 0x7FFF + ((u >> 16) & 1);
    return (short)(u >> 16);
}
__device__ __forceinline__ float bf2f(short s) {
    return __uint_as_float(((unsigned)(unsigned short)s) << 16);
}

// Row of the virtual concatenated [visit; ccs; icd] array.
__device__ __forceinline__ const float* node_row(const float* __restrict__ v,
                                                 const float* __restrict__ c,
                                                 const float* __restrict__ i, int t) {
    return t < NVv ? v + (size_t)t * DD
         : t < NVv + NCc ? c + (size_t)(t - NVv) * DD
                         : i + (size_t)(t - NVv - NCc) * DD;
}

// Per-node MLP via bf16 MFMA, then build the gather tables:
//   TC[n]: 64 chunks of 4 bf16  {el[2l], el[2l+1], c[2l], c[2l+1]}   (512 B/row)
//   O [n]: 128 bf16 offsets                                          (256 B/row)
__global__ __launch_bounds__(256) void node_mlp(
        const float* __restrict__ vc, const float* __restrict__ cc,
        const float* __restrict__ ic,
        const float* __restrict__ vo, const float* __restrict__ co,
        const float* __restrict__ io,
        const float* __restrict__ w1, const float* __restrict__ b1,
        const float* __restrict__ w2, const float* __restrict__ b2,
        short* __restrict__ TC, short* __restrict__ O) {
    __shared__ short wbuf[128][136];
    __shared__ short hbuf[64][136];
    const int tid = threadIdx.x;
    const int lane = tid & 63, wv = tid >> 6;
    const int n0b = blockIdx.x * 64;
    const int n0 = n0b + wv * 16;
    const int colw = lane & 15;              // col within a 16-tile
    const int k0 = (lane >> 4) * 8;          // k sub-offset for A/B frags

    // stage w1 -> bf16 LDS (row-major [j][k])
    for (int idx = tid * 4; idx < DD * DD; idx += 1024) {
        float4 v = *(const float4*)(w1 + idx);
        short* p = &wbuf[idx >> 7][idx & 127];
        p[0] = f2bf(v.x); p[1] = f2bf(v.y); p[2] = f2bf(v.z); p[3] = f2bf(v.w);
    }

    // A frags (layer 1) straight from global: row = n0 + (lane&15)
    int arow = n0 + colw; if (arow >= NNn) arow = NNn - 1;
    const float* ar = node_row(vc, cc, ic, arow);
    short8v a[4];
    #pragma unroll
    for (int kf = 0; kf < 4; ++kf) {
        const float* p = ar + kf * 32 + k0;
        float4 x = *(const float4*)p;
        float4 y = *(const float4*)(p + 4);
        short8v t;
        t[0] = f2bf(x.x); t[1] = f2bf(x.y); t[2] = f2bf(x.z); t[3] = f2bf(x.w);
        t[4] = f2bf(y.x); t[5] = f2bf(y.y); t[6] = f2bf(y.z); t[7] = f2bf(y.w);
        a[kf] = t;
    }
    __syncthreads();

    // layer 1: h = relu(A @ W1^T + b1) -> hbuf
    #pragma unroll
    for (int jt = 0; jt < 8; ++jt) {
        int j = jt * 16 + colw;
        float bb = b1[j];
        f32x4 acc = {bb, bb, bb, bb};
        #pragma unroll
        for (int kf = 0; kf < 4; ++kf) {
            short8v b = *(short8v*)&wbuf[j][kf * 32 + k0];
            acc = __builtin_amdgcn_mfma_f32_16x16x32_bf16(a[kf], b, acc, 0, 0, 0);
        }
        #pragma unroll
        for (int r = 0; r < 4; ++r)
            hbuf[wv * 16 + (lane >> 4) * 4 + r][j] = f2bf(fmaxf(acc[r], 0.f));
    }
    __syncthreads();                         // all waves done reading wbuf(w1)

    // A frags (layer 2) from own hbuf rows
    short8v a2[4];
    #pragma unroll
    for (int kf = 0; kf < 4; ++kf)
        a2[kf] = *(short8v*)&hbuf[wv * 16 + colw][kf * 32 + k0];

    // stage w2 over wbuf
    for (int idx = tid * 4; idx < DD * DD; idx += 1024) {
        float4 v = *(const float4*)(w2 + idx);
        short* p = &wbuf[idx >> 7][idx & 127];
        p[0] = f2bf(v.x); p[1] = f2bf(v.y); p[2] = f2bf(v.z); p[3] = f2bf(v.w);
    }
    __syncthreads();

    // layer 2 + exp -> hbuf as bf16 (hbuf A-frags already consumed)
    #pragma unroll
    for (int jt = 0; jt < 8; ++jt) {
        int j = jt * 16 + colw;
        float bb = b2[j];
        f32x4 acc = {bb, bb, bb, bb};
        #pragma unroll
        for (int kf = 0; kf < 4; ++kf) {
            short8v b = *(short8v*)&wbuf[j][kf * 32 + k0];
            acc = __builtin_amdgcn_mfma_f32_16x16x32_bf16(a2[kf], b, acc, 0, 0, 0);
        }
        #pragma unroll
        for (int r = 0; r < 4; ++r)
            hbuf[wv * 16 + (lane >> 4) * 4 + r][j] = f2bf(__expf(acc[r]));
    }
    __syncthreads();

    // cooperative table writes for rows n0b .. n0b+63
    #pragma unroll
    for (int i = 0; i < 16; ++i) {           // TC: 4096 8B-chunks
        int cid = i * 256 + tid;
        int r = cid >> 6, l = cid & 63;
        int n = n0b + r;
        if (n >= NNn) continue;
        const float* cr = node_row(vc, cc, ic, n);
        float2 cv = *(const float2*)(cr + 2 * l);
        int elp = *(const int*)&hbuf[r][2 * l];         // el[2l] | el[2l+1]<<16
        short4v s;
        s.x = (short)(elp & 0xFFFF);
        s.y = (short)((unsigned)elp >> 16);
        s.z = f2bf(cv.x);
        s.w = f2bf(cv.y);
        *(short4v*)(TC + (size_t)n * 256 + 4 * l) = s;
    }
    #pragma unroll
    for (int i = 0; i < 8; ++i) {            // O: 2048 8B-chunks (4 f32 -> 4 bf16)
        int cid = i * 256 + tid;
        int r = cid >> 5, l = cid & 31;
        int n = n0b + r;
        if (n >= NNn) continue;
        const float* orow = node_row(vo, co, io, n);
        float4 v = *(const float4*)(orow + 4 * l);
        short4v s;
        s.x = f2bf(v.x); s.y = f2bf(v.y); s.z = f2bf(v.z); s.w = f2bf(v.w);
        *(short4v*)(O + (size_t)n * 128 + 4 * l) = s;
    }
}

// ---- CSR build: joint histogram (g1 -> seg h, g2 -> seg NV+h) ----
__global__ void hist(const int* __restrict__ g1, const int* __restrict__ g2,
                     int* __restrict__ cnt) {
    int gid = blockIdx.x * blockDim.x + threadIdx.x;
    if (gid < E1N) {
        int h = g1[gid];
        if (h < NVv) atomicAdd(cnt + h, 1);
    } else if (gid < E1N + E2N) {
        int h = g2[gid - E1N];
        if (h < NVv) atomicAdd(cnt + NVv + h, 1);
    }
}

__global__ __launch_bounds__(1024) void scan_partial(const int* __restrict__ cnt,
                                                     int* __restrict__ bsum) {
    __shared__ int ws[16];
    int tid = threadIdx.x, lane = tid & 63, wvi = tid >> 6;
    int i = blockIdx.x * 1024 + tid;
    int v = (i < SCAN_N) ? cnt[i] : 0;
    #pragma unroll
    for (int off = 32; off; off >>= 1) v += __shfl_xor(v, off);
    if (lane == 0) ws[wvi] = v;
    __syncthreads();
    if (tid == 0) {
        int s = 0;
        #pragma unroll
        for (int w = 0; w < 16; ++w) s += ws[w];
        bsum[blockIdx.x] = s;
    }
}

__global__ __launch_bounds__(128) void scan_mid(const int* __restrict__ bsum,
                                                int* __restrict__ bof,
                                                int* __restrict__ base) {
    __shared__ int wsum0;
    int tid = threadIdx.x, lane = tid & 63, wvi = tid >> 6;
    int v = (tid < SCAN_NB) ? bsum[tid] : 0;
    int incl = v;
    #pragma unroll
    for (int off = 1; off < 64; off <<= 1) {
        int o = __shfl_up(incl, off);
        if (lane >= off) incl += o;
    }
    if (lane == 63 && wvi == 0) wsum0 = incl;
    __syncthreads();
    int excl = incl - v + (wvi ? wsum0 : 0);
    if (tid < SCAN_NB) bof[tid] = excl;
    if (tid == SCAN_NB - 1) base[SCAN_N] = excl + v;   // grand total
}

__global__ __launch_bounds__(1024) void scan_final(const int* __restrict__ cnt,
                                                   const int* __restrict__ bof,
                                                   int* __restrict__ base,
                                                   int* __restrict__ cur) {
    __shared__ int ws[16];
    int tid = threadIdx.x, lane = tid & 63, wvi = tid >> 6;
    int i = blockIdx.x * 1024 + tid;
    int v = (i < SCAN_N) ? cnt[i] : 0;
    int incl = v;
    #pragma unroll
    for (int off = 1; off < 64; off <<= 1) {
        int o = __shfl_up(incl, off);
        if (lane >= off) incl += o;
    }
    if (lane == 63) ws[wvi] = incl;
    __syncthreads();
    int wpre = 0;
    for (int w = 0; w < wvi; ++w) wpre += ws[w];
    int excl = bof[blockIdx.x] + wpre + incl - v;
    if (i < SCAN_N) { base[i] = excl; cur[i] = excl; }
}

__global__ void scatter(const int* __restrict__ g1, const int* __restrict__ g2,
                        int* __restrict__ cur, int* __restrict__ csr) {
    int gid = blockIdx.x * blockDim.x + threadIdx.x;
    if (gid < E1N) {
        int h = g1[gid];
        if (h < NVv) csr[atomicAdd(cur + h, 1)] = g1[E1N + gid];
    } else if (gid < E1N + E2N) {
        int e = gid - E1N;
        int h = g2[e];
        if (h < NVv) csr[atomicAdd(cur + NVv + h, 1)] = g2[E2N + e];
    }
}

// One wave per segment, fused: segment softmax + l2norm (g1 via TC) and
// 5-way relu/segment-max (g1 t>=NV and all g2, via O). No atomics.
__global__ void seg_fused(const int* __restrict__ base, const int* __restrict__ csr,
                          const short* __restrict__ TC, const short* __restrict__ O,
                          float* __restrict__ out0, float* __restrict__ out1) {
    int seg = blockIdx.x * (blockDim.x >> 6) + (threadIdx.x >> 6);
    if (seg >= NVv) return;
    int lane = threadIdx.x & 63;
    float d0 = 0.f, d1 = 0.f, n0 = 0.f, n1 = 0.f;
    float m0 = 0.f, m1 = 0.f;                // 0 == relu floor + empty default

    int s = base[seg], e = base[seg + 1];
    for (int k = s; k < e; ++k) {
        int t = csr[k];
        short4v tc = *(const short4v*)(TC + (size_t)t * 256 + 4 * lane);
        float w0 = bf2f(tc.x), w1 = bf2f(tc.y);
        d0 += w0; d1 += w1;
        n0 = fmaf(w0, bf2f(tc.z), n0);
        n1 = fmaf(w1, bf2f(tc.w), n1);
        if (t >= NVv) {                      // g1 offset mask: t >= NV
            int ov = *(const int*)(O + (size_t)t * 128 + 2 * lane);
            m0 = fmaxf(m0, bf2f((short)(ov & 0xFFFF)));
            m1 = fmaxf(m1, bf2f((short)((unsigned)ov >> 16)));
        }
    }
    s = base[NVv + seg]; e = base[NVv + seg + 1];
    for (int k = s; k < e; ++k) {
        int t = csr[k];
        int ov = *(const int*)(O + (size_t)t * 128 + 2 * lane);
        m0 = fmaxf(m0, bf2f((short)(ov & 0xFFFF)));
        m1 = fmaxf(m1, bf2f((short)((unsigned)ov >> 16)));
    }

    float v0 = d0 > 0.f ? n0 / d0 : 0.f;
    float v1 = d1 > 0.f ? n1 / d1 : 0.f;
    float ss = v0 * v0 + v1 * v1;
    #pragma unroll
    for (int off = 32; off; off >>= 1) ss += __shfl_xor(ss, off);
    float inv = 1.f / fmaxf(sqrtf(ss), 1e-12f);
    size_t b = (size_t)seg * DD + 2 * lane;
    *(float2*)(out0 + b) = make_float2(v0 * inv, v1 * inv);
    *(float2*)(out1 + b) = make_float2(m0, m1);
}

extern "C" void kernel_launch(void* const* d_in, const int* in_sizes, int n_in,
                              void* d_out, int out_size, void* d_ws, size_t ws_size,
                              hipStream_t stream) {
    const float* vc  = (const float*)d_in[0];
    const float* vo  = (const float*)d_in[1];
    const float* cc  = (const float*)d_in[2];
    const float* co  = (const float*)d_in[3];
    const float* ic  = (const float*)d_in[4];
    const float* io  = (const float*)d_in[5];
    // d_in[6] visit_time, d_in[11..14] time-net params: dead (lam == 1.0)
    const float* aw1 = (const float*)d_in[7];
    const float* ab1 = (const float*)d_in[8];
    const float* aw2 = (const float*)d_in[9];
    const float* ab2 = (const float*)d_in[10];
    const int*   g1  = (const int*)d_in[15];
    const int*   g2  = (const int*)d_in[16];

    float* out0 = (float*)d_out;                    // [NV,128] final emb
    float* out1 = out0 + (size_t)NVv * DD;          // [NV,128] final offset

    short* TC  = (short*)d_ws;                      // [NN,256] bf16 {el,el,c,c}
    short* O   = TC + (size_t)NNn * 256;            // [NN,128] bf16 offsets
    int* cnt   = (int*)(O + (size_t)NNn * 128);     // SCAN_N
    int* base  = cnt + SCAN_N;                      // SCAN_N + 1
    int* cur   = base + SCAN_N + 1;                 // SCAN_N
    int* bsum  = cur + SCAN_N;                      // 128
    int* bof   = bsum + 128;                        // 128
    int* csr   = bof + 128;                         // <= E1N + E2N

    hipMemsetAsync(cnt, 0, SCAN_N * sizeof(int), stream);

    node_mlp<<<(NNn + 63) / 64, 256, 0, stream>>>(vc, cc, ic, vo, co, io,
                                                  aw1, ab1, aw2, ab2, TC, O);

    int eblocks = (E1N + E2N + 255) / 256;
    hist<<<eblocks, 256, 0, stream>>>(g1, g2, cnt);
    scan_partial<<<SCAN_NB, 1024, 0, stream>>>(cnt, bsum);
    scan_mid<<<1, 128, 0, stream>>>(bsum, bof, base);
    scan_final<<<SCAN_NB, 1024, 0, stream>>>(cnt, bof, base, cur);
    scatter<<<eblocks, 256, 0, stream>>>(g1, g2, cur, csr);

    seg_fused<<<(NVv + 3) / 4, 256, 0, stream>>>(base, csr, TC, O, out0, out1);
}

// Round 5
// 185.360 us; speedup vs baseline: 11.5676x; 1.1547x over previous
//
#include <hip/hip_runtime.h>
#include <cstdint>

#define NVv 40000
#define NCc 300
#define NIi 7000
#define NNn 47300
#define DD 128
#define E1N 500000
#define E2N 500000

#define SCAN_N (2 * NVv)                     // joint count array (g1 | g2)
#define SCAN_NB ((SCAN_N + 1023) / 1024)     // 79 partial blocks

typedef __attribute__((ext_vector_type(8))) short short8v;
typedef __attribute__((ext_vector_type(4))) short short4v;
typedef __attribute__((ext_vector_type(4))) float f32x4;

__device__ __forceinline__ short f2bf(float f) {   // RNE f32->bf16
    unsigned u = __float_as_uint(f);
    u += 0x7FFF + ((u >> 16) & 1);
    return (short)(u >> 16);
}
__device__ __forceinline__ float bf2f(short s) {
    return __uint_as_float(((unsigned)(unsigned short)s) << 16);
}

// Row of the virtual concatenated [visit; ccs; icd] array.
__device__ __forceinline__ const float* node_row(const float* __restrict__ v,
                                                 const float* __restrict__ c,
                                                 const float* __restrict__ i, int t) {
    return t < NVv ? v + (size_t)t * DD
         : t < NVv + NCc ? c + (size_t)(t - NVv) * DD
                         : i + (size_t)(t - NVv - NCc) * DD;
}

// Per-node MLP via bf16 MFMA, then build the gather tables:
//   TC[n]: 64 chunks of 4 bf16  {el[2l], el[2l+1], c[2l], c[2l+1]}   (512 B/row)
//   O [n]: 128 bf16 offsets                                          (256 B/row)
__global__ __launch_bounds__(256) void node_mlp(
        const float* __restrict__ vc, const float* __restrict__ cc,
        const float* __restrict__ ic,
        const float* __restrict__ vo, const float* __restrict__ co,
        const float* __restrict__ io,
        const float* __restrict__ w1, const float* __restrict__ b1,
        const float* __restrict__ w2, const float* __restrict__ b2,
        short* __restrict__ TC, short* __restrict__ O) {
    __shared__ short wbuf[128][136];
    __shared__ short hbuf[64][136];
    const int tid = threadIdx.x;
    const int lane = tid & 63, wv = tid >> 6;
    const int n0b = blockIdx.x * 64;
    const int n0 = n0b + wv * 16;
    const int colw = lane & 15;              // col within a 16-tile
    const int k0 = (lane >> 4) * 8;          // k sub-offset for A/B frags

    // stage w1 -> bf16 LDS (row-major [j][k])
    for (int idx = tid * 4; idx < DD * DD; idx += 1024) {
        float4 v = *(const float4*)(w1 + idx);
        short* p = &wbuf[idx >> 7][idx & 127];
        p[0] = f2bf(v.x); p[1] = f2bf(v.y); p[2] = f2bf(v.z); p[3] = f2bf(v.w);
    }

    // A frags (layer 1) straight from global: row = n0 + (lane&15)
    int arow = n0 + colw; if (arow >= NNn) arow = NNn - 1;
    const float* ar = node_row(vc, cc, ic, arow);
    short8v a[4];
    #pragma unroll
    for (int kf = 0; kf < 4; ++kf) {
        const float* p = ar + kf * 32 + k0;
        float4 x = *(const float4*)p;
        float4 y = *(const float4*)(p + 4);
        short8v t;
        t[0] = f2bf(x.x); t[1] = f2bf(x.y); t[2] = f2bf(x.z); t[3] = f2bf(x.w);
        t[4] = f2bf(y.x); t[5] = f2bf(y.y); t[6] = f2bf(y.z); t[7] = f2bf(y.w);
        a[kf] = t;
    }
    __syncthreads();

    // layer 1: h = relu(A @ W1^T + b1) -> hbuf
    #pragma unroll
    for (int jt = 0; jt < 8; ++jt) {
        int j = jt * 16 + colw;
        float bb = b1[j];
        f32x4 acc = {bb, bb, bb, bb};
        #pragma unroll
        for (int kf = 0; kf < 4; ++kf) {
            short8v b = *(short8v*)&wbuf[j][kf * 32 + k0];
            acc = __builtin_amdgcn_mfma_f32_16x16x32_bf16(a[kf], b, acc, 0, 0, 0);
        }
        #pragma unroll
        for (int r = 0; r < 4; ++r)
            hbuf[wv * 16 + (lane >> 4) * 4 + r][j] = f2bf(fmaxf(acc[r], 0.f));
    }
    __syncthreads();                         // all waves done reading wbuf(w1)

    // A frags (layer 2) from own hbuf rows
    short8v a2[4];
    #pragma unroll
    for (int kf = 0; kf < 4; ++kf)
        a2[kf] = *(short8v*)&hbuf[wv * 16 + colw][kf * 32 + k0];

    // stage w2 over wbuf
    for (int idx = tid * 4; idx < DD * DD; idx += 1024) {
        float4 v = *(const float4*)(w2 + idx);
        short* p = &wbuf[idx >> 7][idx & 127];
        p[0] = f2bf(v.x); p[1] = f2bf(v.y); p[2] = f2bf(v.z); p[3] = f2bf(v.w);
    }
    __syncthreads();

    // layer 2 + exp -> hbuf as bf16 (hbuf A-frags already consumed)
    #pragma unroll
    for (int jt = 0; jt < 8; ++jt) {
        int j = jt * 16 + colw;
        float bb = b2[j];
        f32x4 acc = {bb, bb, bb, bb};
        #pragma unroll
        for (int kf = 0; kf < 4; ++kf) {
            short8v b = *(short8v*)&wbuf[j][kf * 32 + k0];
            acc = __builtin_amdgcn_mfma_f32_16x16x32_bf16(a2[kf], b, acc, 0, 0, 0);
        }
        #pragma unroll
        for (int r = 0; r < 4; ++r)
            hbuf[wv * 16 + (lane >> 4) * 4 + r][j] = f2bf(__expf(acc[r]));
    }
    __syncthreads();

    // cooperative table writes for rows n0b .. n0b+63
    #pragma unroll
    for (int i = 0; i < 16; ++i) {           // TC: 4096 8B-chunks
        int cid = i * 256 + tid;
        int r = cid >> 6, l = cid & 63;
        int n = n0b + r;
        if (n >= NNn) continue;
        const float* cr = node_row(vc, cc, ic, n);
        float2 cv = *(const float2*)(cr + 2 * l);
        int elp = *(const int*)&hbuf[r][2 * l];         // el[2l] | el[2l+1]<<16
        short4v s;
        s.x = (short)(elp & 0xFFFF);
        s.y = (short)((unsigned)elp >> 16);
        s.z = f2bf(cv.x);
        s.w = f2bf(cv.y);
        *(short4v*)(TC + (size_t)n * 256 + 4 * l) = s;
    }
    #pragma unroll
    for (int i = 0; i < 8; ++i) {            // O: 2048 8B-chunks (4 f32 -> 4 bf16)
        int cid = i * 256 + tid;
        int r = cid >> 5, l = cid & 31;
        int n = n0b + r;
        if (n >= NNn) continue;
        const float* orow = node_row(vo, co, io, n);
        float4 v = *(const float4*)(orow + 4 * l);
        short4v s;
        s.x = f2bf(v.x); s.y = f2bf(v.y); s.z = f2bf(v.z); s.w = f2bf(v.w);
        *(short4v*)(O + (size_t)n * 128 + 4 * l) = s;
    }
}

// ---- CSR build: joint histogram (g1 -> seg h, g2 -> seg NV+h) ----
__global__ void hist(const int* __restrict__ g1, const int* __restrict__ g2,
                     int* __restrict__ cnt) {
    int gid = blockIdx.x * blockDim.x + threadIdx.x;
    if (gid < E1N) {
        int h = g1[gid];
        if (h < NVv) atomicAdd(cnt + h, 1);
    } else if (gid < E1N + E2N) {
        int h = g2[gid - E1N];
        if (h < NVv) atomicAdd(cnt + NVv + h, 1);
    }
}

__global__ __launch_bounds__(1024) void scan_partial(const int* __restrict__ cnt,
                                                     int* __restrict__ bsum) {
    __shared__ int ws[16];
    int tid = threadIdx.x, lane = tid & 63, wvi = tid >> 6;
    int i = blockIdx.x * 1024 + tid;
    int v = (i < SCAN_N) ? cnt[i] : 0;
    #pragma unroll
    for (int off = 32; off; off >>= 1) v += __shfl_xor(v, off);
    if (lane == 0) ws[wvi] = v;
    __syncthreads();
    if (tid == 0) {
        int s = 0;
        #pragma unroll
        for (int w = 0; w < 16; ++w) s += ws[w];
        bsum[blockIdx.x] = s;
    }
}

// Final scan; block offset = reduce(bsum[0..blockIdx)) computed in-kernel
// (replaces the separate scan_mid launch).
__global__ __launch_bounds__(1024) void scan_final(const int* __restrict__ cnt,
                                                   const int* __restrict__ bsum,
                                                   int* __restrict__ base,
                                                   int* __restrict__ cur) {
    __shared__ int ws[16];
    __shared__ int s_off;
    int tid = threadIdx.x, lane = tid & 63, wvi = tid >> 6;

    // block offset: sum of preceding blocks' totals
    int pre = 0;
    for (int j = tid; j < (int)blockIdx.x; j += 1024) pre += bsum[j];
    #pragma unroll
    for (int off = 32; off; off >>= 1) pre += __shfl_xor(pre, off);
    if (lane == 0) ws[wvi] = pre;
    __syncthreads();
    if (tid == 0) {
        int s = 0;
        #pragma unroll
        for (int w = 0; w < 16; ++w) s += ws[w];
        s_off = s;
    }
    __syncthreads();
    int boff = s_off;
    __syncthreads();                         // ws reuse below

    int i = blockIdx.x * 1024 + tid;
    int v = (i < SCAN_N) ? cnt[i] : 0;
    int incl = v;
    #pragma unroll
    for (int off = 1; off < 64; off <<= 1) {
        int o = __shfl_up(incl, off);
        if (lane >= off) incl += o;
    }
    if (lane == 63) ws[wvi] = incl;
    __syncthreads();
    int wpre = 0;
    for (int w = 0; w < wvi; ++w) wpre += ws[w];
    int excl = boff + wpre + incl - v;
    if (i < SCAN_N) { base[i] = excl; cur[i] = excl; }
    if (i == SCAN_N - 1) base[SCAN_N] = excl + v;   // grand total
}

__global__ void scatter(const int* __restrict__ g1, const int* __restrict__ g2,
                        int* __restrict__ cur, int* __restrict__ csr) {
    int gid = blockIdx.x * blockDim.x + threadIdx.x;
    if (gid < E1N) {
        int h = g1[gid];
        if (h < NVv) csr[atomicAdd(cur + h, 1)] = g1[E1N + gid];
    } else if (gid < E1N + E2N) {
        int e = gid - E1N;
        int h = g2[e];
        if (h < NVv) csr[atomicAdd(cur + NVv + h, 1)] = g2[E2N + e];
    }
}

__device__ __forceinline__ void acc_tc(short4v tc, float& d0, float& d1,
                                       float& n0, float& n1) {
    float w0 = bf2f(tc.x), w1 = bf2f(tc.y);
    d0 += w0; d1 += w1;
    n0 = fmaf(w0, bf2f(tc.z), n0);
    n1 = fmaf(w1, bf2f(tc.w), n1);
}
__device__ __forceinline__ void acc_o(int ov, bool en, float& m0, float& m1) {
    if (en) {
        m0 = fmaxf(m0, bf2f((short)(ov & 0xFFFF)));
        m1 = fmaxf(m1, bf2f((short)((unsigned)ov >> 16)));
    }
}

// One wave per segment, fused softmax+l2norm and 5-way relu/segment-max.
// MLP-boosted: csr indices batched 64-at-a-time via one coalesced load +
// __shfl broadcast; gathers issued in independent batches of 4 (TC+O) / 8 (O).
__global__ void seg_fused(const int* __restrict__ base, const int* __restrict__ csr,
                          const short* __restrict__ TC, const short* __restrict__ O,
                          float* __restrict__ out0, float* __restrict__ out1) {
    int seg = __builtin_amdgcn_readfirstlane(
        blockIdx.x * (blockDim.x >> 6) + (threadIdx.x >> 6));
    if (seg >= NVv) return;
    int lane = threadIdx.x & 63;
    float d0 = 0.f, d1 = 0.f, n0 = 0.f, n1 = 0.f;
    float m0 = 0.f, m1 = 0.f;                // 0 == relu floor + empty default

    // ---- graph-1 edges: softmax (TC) + masked offset max (O, t>=NV) ----
    int s = base[seg], e = base[seg + 1];
    for (int c = s; c < e; c += 64) {
        int lim = e - c; if (lim > 64) lim = 64;
        int tl = 0;
        if (lane < lim) tl = csr[c + lane];
        int k = 0;
        for (; k + 4 <= lim; k += 4) {
            int t0 = __shfl(tl, k + 0), t1 = __shfl(tl, k + 1),
                t2 = __shfl(tl, k + 2), t3 = __shfl(tl, k + 3);
            short4v a0 = *(const short4v*)(TC + ((size_t)t0 << 8) + 4 * lane);
            short4v a1 = *(const short4v*)(TC + ((size_t)t1 << 8) + 4 * lane);
            short4v a2 = *(const short4v*)(TC + ((size_t)t2 << 8) + 4 * lane);
            short4v a3 = *(const short4v*)(TC + ((size_t)t3 << 8) + 4 * lane);
            int o0 = *(const int*)(O + ((size_t)t0 << 7) + 2 * lane);
            int o1 = *(const int*)(O + ((size_t)t1 << 7) + 2 * lane);
            int o2 = *(const int*)(O + ((size_t)t2 << 7) + 2 * lane);
            int o3 = *(const int*)(O + ((size_t)t3 << 7) + 2 * lane);
            acc_tc(a0, d0, d1, n0, n1);
            acc_tc(a1, d0, d1, n0, n1);
            acc_tc(a2, d0, d1, n0, n1);
            acc_tc(a3, d0, d1, n0, n1);
            acc_o(o0, t0 >= NVv, m0, m1);
            acc_o(o1, t1 >= NVv, m0, m1);
            acc_o(o2, t2 >= NVv, m0, m1);
            acc_o(o3, t3 >= NVv, m0, m1);
        }
        for (; k < lim; ++k) {
            int t = __shfl(tl, k);
            short4v a = *(const short4v*)(TC + ((size_t)t << 8) + 4 * lane);
            acc_tc(a, d0, d1, n0, n1);
            if (t >= NVv) {
                int ov = *(const int*)(O + ((size_t)t << 7) + 2 * lane);
                acc_o(ov, true, m0, m1);
            }
        }
    }

    // ---- graph-2 edges: offset max only ----
    s = base[NVv + seg]; e = base[NVv + seg + 1];
    for (int c = s; c < e; c += 64) {
        int lim = e - c; if (lim > 64) lim = 64;
        int tl = 0;
        if (lane < lim) tl = csr[c + lane];
        int k = 0;
        for (; k + 8 <= lim; k += 8) {
            int t0 = __shfl(tl, k + 0), t1 = __shfl(tl, k + 1),
                t2 = __shfl(tl, k + 2), t3 = __shfl(tl, k + 3),
                t4 = __shfl(tl, k + 4), t5 = __shfl(tl, k + 5),
                t6 = __shfl(tl, k + 6), t7 = __shfl(tl, k + 7);
            int o0 = *(const int*)(O + ((size_t)t0 << 7) + 2 * lane);
            int o1 = *(const int*)(O + ((size_t)t1 << 7) + 2 * lane);
            int o2 = *(const int*)(O + ((size_t)t2 << 7) + 2 * lane);
            int o3 = *(const int*)(O + ((size_t)t3 << 7) + 2 * lane);
            int o4 = *(const int*)(O + ((size_t)t4 << 7) + 2 * lane);
            int o5 = *(const int*)(O + ((size_t)t5 << 7) + 2 * lane);
            int o6 = *(const int*)(O + ((size_t)t6 << 7) + 2 * lane);
            int o7 = *(const int*)(O + ((size_t)t7 << 7) + 2 * lane);
            acc_o(o0, true, m0, m1); acc_o(o1, true, m0, m1);
            acc_o(o2, true, m0, m1); acc_o(o3, true, m0, m1);
            acc_o(o4, true, m0, m1); acc_o(o5, true, m0, m1);
            acc_o(o6, true, m0, m1); acc_o(o7, true, m0, m1);
        }
        for (; k < lim; ++k) {
            int t = __shfl(tl, k);
            int ov = *(const int*)(O + ((size_t)t << 7) + 2 * lane);
            acc_o(ov, true, m0, m1);
        }
    }

    float v0 = d0 > 0.f ? n0 / d0 : 0.f;
    float v1 = d1 > 0.f ? n1 / d1 : 0.f;
    float ss = v0 * v0 + v1 * v1;
    #pragma unroll
    for (int off = 32; off; off >>= 1) ss += __shfl_xor(ss, off);
    float inv = 1.f / fmaxf(sqrtf(ss), 1e-12f);
    size_t b = (size_t)seg * DD + 2 * lane;
    *(float2*)(out0 + b) = make_float2(v0 * inv, v1 * inv);
    *(float2*)(out1 + b) = make_float2(m0, m1);
}

extern "C" void kernel_launch(void* const* d_in, const int* in_sizes, int n_in,
                              void* d_out, int out_size, void* d_ws, size_t ws_size,
                              hipStream_t stream) {
    const float* vc  = (const float*)d_in[0];
    const float* vo  = (const float*)d_in[1];
    const float* cc  = (const float*)d_in[2];
    const float* co  = (const float*)d_in[3];
    const float* ic  = (const float*)d_in[4];
    const float* io  = (const float*)d_in[5];
    // d_in[6] visit_time, d_in[11..14] time-net params: dead (lam == 1.0)
    const float* aw1 = (const float*)d_in[7];
    const float* ab1 = (const float*)d_in[8];
    const float* aw2 = (const float*)d_in[9];
    const float* ab2 = (const float*)d_in[10];
    const int*   g1  = (const int*)d_in[15];
    const int*   g2  = (const int*)d_in[16];

    float* out0 = (float*)d_out;                    // [NV,128] final emb
    float* out1 = out0 + (size_t)NVv * DD;          // [NV,128] final offset

    short* TC  = (short*)d_ws;                      // [NN,256] bf16 {el,el,c,c}
    short* O   = TC + (size_t)NNn * 256;            // [NN,128] bf16 offsets
    int* cnt   = (int*)(O + (size_t)NNn * 128);     // SCAN_N
    int* base  = cnt + SCAN_N;                      // SCAN_N + 1
    int* cur   = base + SCAN_N + 1;                 // SCAN_N
    int* bsum  = cur + SCAN_N;                      // 128
    int* csr   = bsum + 128;                        // <= E1N + E2N

    hipMemsetAsync(cnt, 0, SCAN_N * sizeof(int), stream);

    node_mlp<<<(NNn + 63) / 64, 256, 0, stream>>>(vc, cc, ic, vo, co, io,
                                                  aw1, ab1, aw2, ab2, TC, O);

    int eblocks = (E1N + E2N + 255) / 256;
    hist<<<eblocks, 256, 0, stream>>>(g1, g2, cnt);
    scan_partial<<<SCAN_NB, 1024, 0, stream>>>(cnt, bsum);
    scan_final<<<SCAN_NB, 1024, 0, stream>>>(cnt, bsum, base, cur);
    scatter<<<eblocks, 256, 0, stream>>>(g1, g2, cur, csr);

    seg_fused<<<(NVv + 3) / 4, 256, 0, stream>>>(base, csr, TC, O, out0, out1);
}

// Round 6
// 176.994 us; speedup vs baseline: 12.1144x; 1.0473x over previous
//
#include <hip/hip_runtime.h>
#include <cstdint>

#define NVv 40000
#define NCc 300
#define NIi 7000
#define NNn 47300
#define DD 128
#define E1N 500000
#define E2N 500000

#define SCAN_N (3 * NVv)                     // sections: g1hi | g1lo | g2
#define SCAN_NB ((SCAN_N + 1023) / 1024)     // 118 partial blocks

typedef __attribute__((ext_vector_type(8))) short short8v;
typedef __attribute__((ext_vector_type(4))) short short4v;
typedef __attribute__((ext_vector_type(4))) float f32x4;

__device__ __forceinline__ short f2bf(float f) {   // RNE f32->bf16
    unsigned u = __float_as_uint(f);
    u += 0x7FFF + ((u >> 16) & 1);
    return (short)(u >> 16);
}
__device__ __forceinline__ float bf2f(short s) {
    return __uint_as_float(((unsigned)(unsigned short)s) << 16);
}

// Row of the virtual concatenated [visit; ccs; icd] array.
__device__ __forceinline__ const float* node_row(const float* __restrict__ v,
                                                 const float* __restrict__ c,
                                                 const float* __restrict__ i, int t) {
    return t < NVv ? v + (size_t)t * DD
         : t < NVv + NCc ? c + (size_t)(t - NVv) * DD
                         : i + (size_t)(t - NVv - NCc) * DD;
}

// Per-node MLP via bf16 MFMA, then build the gather tables:
//   TC[n]: 64 chunks of 4 bf16  {el[2l], el[2l+1], c[2l], c[2l+1]}   (512 B/row)
//   O [n]: 128 bf16 offsets                                          (256 B/row)
__global__ __launch_bounds__(256) void node_mlp(
        const float* __restrict__ vc, const float* __restrict__ cc,
        const float* __restrict__ ic,
        const float* __restrict__ vo, const float* __restrict__ co,
        const float* __restrict__ io,
        const float* __restrict__ w1, const float* __restrict__ b1,
        const float* __restrict__ w2, const float* __restrict__ b2,
        short* __restrict__ TC, short* __restrict__ O) {
    __shared__ short wbuf[128][136];
    __shared__ short hbuf[64][136];
    const int tid = threadIdx.x;
    const int lane = tid & 63, wv = tid >> 6;
    const int n0b = blockIdx.x * 64;
    const int n0 = n0b + wv * 16;
    const int colw = lane & 15;              // col within a 16-tile
    const int k0 = (lane >> 4) * 8;          // k sub-offset for A/B frags

    // stage w1 -> bf16 LDS (row-major [j][k])
    for (int idx = tid * 4; idx < DD * DD; idx += 1024) {
        float4 v = *(const float4*)(w1 + idx);
        short* p = &wbuf[idx >> 7][idx & 127];
        p[0] = f2bf(v.x); p[1] = f2bf(v.y); p[2] = f2bf(v.z); p[3] = f2bf(v.w);
    }

    // A frags (layer 1) straight from global: row = n0 + (lane&15)
    int arow = n0 + colw; if (arow >= NNn) arow = NNn - 1;
    const float* ar = node_row(vc, cc, ic, arow);
    short8v a[4];
    #pragma unroll
    for (int kf = 0; kf < 4; ++kf) {
        const float* p = ar + kf * 32 + k0;
        float4 x = *(const float4*)p;
        float4 y = *(const float4*)(p + 4);
        short8v t;
        t[0] = f2bf(x.x); t[1] = f2bf(x.y); t[2] = f2bf(x.z); t[3] = f2bf(x.w);
        t[4] = f2bf(y.x); t[5] = f2bf(y.y); t[6] = f2bf(y.z); t[7] = f2bf(y.w);
        a[kf] = t;
    }
    __syncthreads();

    // layer 1: h = relu(A @ W1^T + b1) -> hbuf
    #pragma unroll
    for (int jt = 0; jt < 8; ++jt) {
        int j = jt * 16 + colw;
        float bb = b1[j];
        f32x4 acc = {bb, bb, bb, bb};
        #pragma unroll
        for (int kf = 0; kf < 4; ++kf) {
            short8v b = *(short8v*)&wbuf[j][kf * 32 + k0];
            acc = __builtin_amdgcn_mfma_f32_16x16x32_bf16(a[kf], b, acc, 0, 0, 0);
        }
        #pragma unroll
        for (int r = 0; r < 4; ++r)
            hbuf[wv * 16 + (lane >> 4) * 4 + r][j] = f2bf(fmaxf(acc[r], 0.f));
    }
    __syncthreads();                         // all waves done reading wbuf(w1)

    // A frags (layer 2) from own hbuf rows
    short8v a2[4];
    #pragma unroll
    for (int kf = 0; kf < 4; ++kf)
        a2[kf] = *(short8v*)&hbuf[wv * 16 + colw][kf * 32 + k0];

    // stage w2 over wbuf
    for (int idx = tid * 4; idx < DD * DD; idx += 1024) {
        float4 v = *(const float4*)(w2 + idx);
        short* p = &wbuf[idx >> 7][idx & 127];
        p[0] = f2bf(v.x); p[1] = f2bf(v.y); p[2] = f2bf(v.z); p[3] = f2bf(v.w);
    }
    __syncthreads();

    // layer 2 + exp -> hbuf as bf16 (hbuf A-frags already consumed)
    #pragma unroll
    for (int jt = 0; jt < 8; ++jt) {
        int j = jt * 16 + colw;
        float bb = b2[j];
        f32x4 acc = {bb, bb, bb, bb};
        #pragma unroll
        for (int kf = 0; kf < 4; ++kf) {
            short8v b = *(short8v*)&wbuf[j][kf * 32 + k0];
            acc = __builtin_amdgcn_mfma_f32_16x16x32_bf16(a2[kf], b, acc, 0, 0, 0);
        }
        #pragma unroll
        for (int r = 0; r < 4; ++r)
            hbuf[wv * 16 + (lane >> 4) * 4 + r][j] = f2bf(__expf(acc[r]));
    }
    __syncthreads();

    // cooperative table writes for rows n0b .. n0b+63
    #pragma unroll
    for (int i = 0; i < 16; ++i) {           // TC: 4096 8B-chunks
        int cid = i * 256 + tid;
        int r = cid >> 6, l = cid & 63;
        int n = n0b + r;
        if (n >= NNn) continue;
        const float* cr = node_row(vc, cc, ic, n);
        float2 cv = *(const float2*)(cr + 2 * l);
        int elp = *(const int*)&hbuf[r][2 * l];         // el[2l] | el[2l+1]<<16
        short4v s;
        s.x = (short)(elp & 0xFFFF);
        s.y = (short)((unsigned)elp >> 16);
        s.z = f2bf(cv.x);
        s.w = f2bf(cv.y);
        *(short4v*)(TC + (size_t)n * 256 + 4 * l) = s;
    }
    #pragma unroll
    for (int i = 0; i < 8; ++i) {            // O: 2048 8B-chunks (4 f32 -> 4 bf16)
        int cid = i * 256 + tid;
        int r = cid >> 5, l = cid & 31;
        int n = n0b + r;
        if (n >= NNn) continue;
        const float* orow = node_row(vo, co, io, n);
        float4 v = *(const float4*)(orow + 4 * l);
        short4v s;
        s.x = f2bf(v.x); s.y = f2bf(v.y); s.z = f2bf(v.z); s.w = f2bf(v.w);
        *(short4v*)(O + (size_t)n * 128 + 4 * l) = s;
    }
}

// ---- CSR build: 3-section histogram (g1&t>=NV -> h; g1&t<NV -> NV+h; g2 -> 2NV+h)
__global__ void hist(const int* __restrict__ g1, const int* __restrict__ g2,
                     int* __restrict__ cnt) {
    int gid = blockIdx.x * blockDim.x + threadIdx.x;
    if (gid < E1N) {
        int h = g1[gid];
        if (h < NVv) {
            int t = g1[E1N + gid];
            atomicAdd(cnt + (t >= NVv ? h : NVv + h), 1);
        }
    } else if (gid < E1N + E2N) {
        int h = g2[gid - E1N];
        if (h < NVv) atomicAdd(cnt + 2 * NVv + h, 1);
    }
}

__global__ __launch_bounds__(1024) void scan_partial(const int* __restrict__ cnt,
                                                     int* __restrict__ bsum) {
    __shared__ int ws[16];
    int tid = threadIdx.x, lane = tid & 63, wvi = tid >> 6;
    int i = blockIdx.x * 1024 + tid;
    int v = (i < SCAN_N) ? cnt[i] : 0;
    #pragma unroll
    for (int off = 32; off; off >>= 1) v += __shfl_xor(v, off);
    if (lane == 0) ws[wvi] = v;
    __syncthreads();
    if (tid == 0) {
        int s = 0;
        #pragma unroll
        for (int w = 0; w < 16; ++w) s += ws[w];
        bsum[blockIdx.x] = s;
    }
}

// Final scan; block offset = reduce(bsum[0..blockIdx)) computed in-kernel.
__global__ __launch_bounds__(1024) void scan_final(const int* __restrict__ cnt,
                                                   const int* __restrict__ bsum,
                                                   int* __restrict__ base,
                                                   int* __restrict__ cur) {
    __shared__ int ws[16];
    __shared__ int s_off;
    int tid = threadIdx.x, lane = tid & 63, wvi = tid >> 6;

    int pre = 0;
    for (int j = tid; j < (int)blockIdx.x; j += 1024) pre += bsum[j];
    #pragma unroll
    for (int off = 32; off; off >>= 1) pre += __shfl_xor(pre, off);
    if (lane == 0) ws[wvi] = pre;
    __syncthreads();
    if (tid == 0) {
        int s = 0;
        #pragma unroll
        for (int w = 0; w < 16; ++w) s += ws[w];
        s_off = s;
    }
    __syncthreads();
    int boff = s_off;
    __syncthreads();                         // ws reuse below

    int i = blockIdx.x * 1024 + tid;
    int v = (i < SCAN_N) ? cnt[i] : 0;
    int incl = v;
    #pragma unroll
    for (int off = 1; off < 64; off <<= 1) {
        int o = __shfl_up(incl, off);
        if (lane >= off) incl += o;
    }
    if (lane == 63) ws[wvi] = incl;
    __syncthreads();
    int wpre = 0;
    for (int w = 0; w < wvi; ++w) wpre += ws[w];
    int excl = boff + wpre + incl - v;
    if (i < SCAN_N) { base[i] = excl; cur[i] = excl; }
    if (i == SCAN_N - 1) base[SCAN_N] = excl + v;   // grand total
}

__global__ void scatter(const int* __restrict__ g1, const int* __restrict__ g2,
                        int* __restrict__ cur, unsigned short* __restrict__ csr) {
    int gid = blockIdx.x * blockDim.x + threadIdx.x;
    if (gid < E1N) {
        int h = g1[gid];
        if (h < NVv) {
            int t = g1[E1N + gid];
            int sec = t >= NVv ? h : NVv + h;
            csr[atomicAdd(cur + sec, 1)] = (unsigned short)t;
        }
    } else if (gid < E1N + E2N) {
        int e = gid - E1N;
        int h = g2[e];
        if (h < NVv)
            csr[atomicAdd(cur + 2 * NVv + h, 1)] = (unsigned short)g2[E2N + e];
    }
}

__device__ __forceinline__ void acc_tc(short4v tc, float& d0, float& d1,
                                       float& n0, float& n1) {
    float w0 = bf2f(tc.x), w1 = bf2f(tc.y);
    d0 += w0; d1 += w1;
    n0 = fmaf(w0, bf2f(tc.z), n0);
    n1 = fmaf(w1, bf2f(tc.w), n1);
}
__device__ __forceinline__ void acc_o(int ov, float& m0, float& m1) {
    m0 = fmaxf(m0, bf2f((short)(ov & 0xFFFF)));
    m1 = fmaxf(m1, bf2f((short)((unsigned)ov >> 16)));
}

// One wave per segment. Sections: g1hi = TC+O (no mask), g1lo = TC only,
// g2 = O only. Edge indices batched via coalesced ushort load + readlane
// broadcast (wave-uniform k -> SGPR t -> scalar-base gathers).
__global__ void seg_fused(const int* __restrict__ base,
                          const unsigned short* __restrict__ csr,
                          const short* __restrict__ TC, const short* __restrict__ O,
                          float* __restrict__ out0, float* __restrict__ out1) {
    int seg = __builtin_amdgcn_readfirstlane(
        blockIdx.x * (blockDim.x >> 6) + (threadIdx.x >> 6));
    if (seg >= NVv) return;
    int lane = threadIdx.x & 63;
    float d0 = 0.f, d1 = 0.f, n0 = 0.f, n1 = 0.f;
    float m0 = 0.f, m1 = 0.f;                // 0 == relu floor + empty default

    // ---- g1 & t>=NV: softmax + offset max, unconditional ----
    int s = base[seg], e = base[seg + 1];
    for (int c = s; c < e; c += 64) {
        int lim = e - c; if (lim > 64) lim = 64;
        int tl = (lane < lim) ? (int)csr[c + lane] : 0;
        int k = 0;
        for (; k + 4 <= lim; k += 4) {
            short4v a[4]; int o[4];
            #pragma unroll
            for (int u = 0; u < 4; ++u) {
                int t = __builtin_amdgcn_readlane(tl, k + u);
                a[u] = *(const short4v*)(TC + ((size_t)t << 8) + 4 * lane);
                o[u] = *(const int*)(O + ((size_t)t << 7) + 2 * lane);
            }
            #pragma unroll
            for (int u = 0; u < 4; ++u) {
                acc_tc(a[u], d0, d1, n0, n1);
                acc_o(o[u], m0, m1);
            }
        }
        for (; k < lim; ++k) {
            int t = __builtin_amdgcn_readlane(tl, k);
            short4v a = *(const short4v*)(TC + ((size_t)t << 8) + 4 * lane);
            int ov = *(const int*)(O + ((size_t)t << 7) + 2 * lane);
            acc_tc(a, d0, d1, n0, n1);
            acc_o(ov, m0, m1);
        }
    }

    // ---- g1 & t<NV: softmax only, batch 8 ----
    s = base[NVv + seg]; e = base[NVv + seg + 1];
    for (int c = s; c < e; c += 64) {
        int lim = e - c; if (lim > 64) lim = 64;
        int tl = (lane < lim) ? (int)csr[c + lane] : 0;
        int k = 0;
        for (; k + 8 <= lim; k += 8) {
            short4v a[8];
            #pragma unroll
            for (int u = 0; u < 8; ++u) {
                int t = __builtin_amdgcn_readlane(tl, k + u);
                a[u] = *(const short4v*)(TC + ((size_t)t << 8) + 4 * lane);
            }
            #pragma unroll
            for (int u = 0; u < 8; ++u) acc_tc(a[u], d0, d1, n0, n1);
        }
        for (; k < lim; ++k) {
            int t = __builtin_amdgcn_readlane(tl, k);
            short4v a = *(const short4v*)(TC + ((size_t)t << 8) + 4 * lane);
            acc_tc(a, d0, d1, n0, n1);
        }
    }

    // ---- g2: offset max only, batch 8 ----
    s = base[2 * NVv + seg]; e = base[2 * NVv + seg + 1];
    for (int c = s; c < e; c += 64) {
        int lim = e - c; if (lim > 64) lim = 64;
        int tl = (lane < lim) ? (int)csr[c + lane] : 0;
        int k = 0;
        for (; k + 8 <= lim; k += 8) {
            int o[8];
            #pragma unroll
            for (int u = 0; u < 8; ++u) {
                int t = __builtin_amdgcn_readlane(tl, k + u);
                o[u] = *(const int*)(O + ((size_t)t << 7) + 2 * lane);
            }
            #pragma unroll
            for (int u = 0; u < 8; ++u) acc_o(o[u], m0, m1);
        }
        for (; k < lim; ++k) {
            int t = __builtin_amdgcn_readlane(tl, k);
            int ov = *(const int*)(O + ((size_t)t << 7) + 2 * lane);
            acc_o(ov, m0, m1);
        }
    }

    float v0 = d0 > 0.f ? n0 / d0 : 0.f;
    float v1 = d1 > 0.f ? n1 / d1 : 0.f;
    float ss = v0 * v0 + v1 * v1;
    #pragma unroll
    for (int off = 32; off; off >>= 1) ss += __shfl_xor(ss, off);
    float inv = 1.f / fmaxf(sqrtf(ss), 1e-12f);
    size_t b = (size_t)seg * DD + 2 * lane;
    *(float2*)(out0 + b) = make_float2(v0 * inv, v1 * inv);
    *(float2*)(out1 + b) = make_float2(m0, m1);
}

extern "C" void kernel_launch(void* const* d_in, const int* in_sizes, int n_in,
                              void* d_out, int out_size, void* d_ws, size_t ws_size,
                              hipStream_t stream) {
    const float* vc  = (const float*)d_in[0];
    const float* vo  = (const float*)d_in[1];
    const float* cc  = (const float*)d_in[2];
    const float* co  = (const float*)d_in[3];
    const float* ic  = (const float*)d_in[4];
    const float* io  = (const float*)d_in[5];
    // d_in[6] visit_time, d_in[11..14] time-net params: dead (lam == 1.0)
    const float* aw1 = (const float*)d_in[7];
    const float* ab1 = (const float*)d_in[8];
    const float* aw2 = (const float*)d_in[9];
    const float* ab2 = (const float*)d_in[10];
    const int*   g1  = (const int*)d_in[15];
    const int*   g2  = (const int*)d_in[16];

    float* out0 = (float*)d_out;                    // [NV,128] final emb
    float* out1 = out0 + (size_t)NVv * DD;          // [NV,128] final offset

    short* TC  = (short*)d_ws;                      // [NN,256] bf16 {el,el,c,c}
    short* O   = TC + (size_t)NNn * 256;            // [NN,128] bf16 offsets
    int* cnt   = (int*)(O + (size_t)NNn * 128);     // SCAN_N
    int* base  = cnt + SCAN_N;                      // SCAN_N + 1
    int* cur   = base + SCAN_N + 1;                 // SCAN_N
    int* bsum  = cur + SCAN_N;                      // 128
    unsigned short* csr = (unsigned short*)(bsum + 128);   // <= E1N + E2N

    hipMemsetAsync(cnt, 0, SCAN_N * sizeof(int), stream);

    node_mlp<<<(NNn + 63) / 64, 256, 0, stream>>>(vc, cc, ic, vo, co, io,
                                                  aw1, ab1, aw2, ab2, TC, O);

    int eblocks = (E1N + E2N + 255) / 256;
    hist<<<eblocks, 256, 0, stream>>>(g1, g2, cnt);
    scan_partial<<<SCAN_NB, 1024, 0, stream>>>(cnt, bsum);
    scan_final<<<SCAN_NB, 1024, 0, stream>>>(cnt, bsum, base, cur);
    scatter<<<eblocks, 256, 0, stream>>>(g1, g2, cur, csr);

    seg_fused<<<(NVv + 3) / 4, 256, 0, stream>>>(base, csr, TC, O, out0, out1);
}

// Round 7
// 167.495 us; speedup vs baseline: 12.8015x; 1.0567x over previous
//
#include <hip/hip_runtime.h>
#include <cstdint>

#define NVv 40000
#define NCc 300
#define NIi 7000
#define NNn 47300
#define DD 128
#define E1N 500000
#define E2N 500000

#define SCAN_N (3 * NVv)                     // sections: g1hi | g1lo | g2
#define SCAN_NB ((SCAN_N + 1023) / 1024)
#define MLPB ((NNn + 63) / 64)               // 740 MLP blocks
#define EBLK ((E1N + E2N + 255) / 256)       // 3907 hist blocks

typedef __attribute__((ext_vector_type(8))) short short8v;
typedef __attribute__((ext_vector_type(4))) short short4v;
typedef __attribute__((ext_vector_type(4))) float f32x4;

__device__ __forceinline__ short f2bf(float f) {   // RNE f32->bf16
    unsigned u = __float_as_uint(f);
    u += 0x7FFF + ((u >> 16) & 1);
    return (short)(u >> 16);
}
__device__ __forceinline__ float bf2f(short s) {
    return __uint_as_float(((unsigned)(unsigned short)s) << 16);
}

// Row of the virtual concatenated [visit; ccs; icd] array.
__device__ __forceinline__ const float* node_row(const float* __restrict__ v,
                                                 const float* __restrict__ c,
                                                 const float* __restrict__ i, int t) {
    return t < NVv ? v + (size_t)t * DD
         : t < NVv + NCc ? c + (size_t)(t - NVv) * DD
                         : i + (size_t)(t - NVv - NCc) * DD;
}

// Fused: blocks [0,MLPB) run the node MLP + table build; blocks [MLPB,..) run
// the edge histogram (independent work, hidden under the MLP).
// Table layout (for 2-edges-per-wave gathers in seg_fused):
//   TC[n]: 32 chunks x 16B, chunk q = bf16 {el[4q..4q+3], c[4q..4q+3]}  (512 B)
//   O [n]: 128 bf16 offsets                                             (256 B)
__global__ __launch_bounds__(256) void mlp_hist(
        const float* __restrict__ vc, const float* __restrict__ cc,
        const float* __restrict__ ic,
        const float* __restrict__ vo, const float* __restrict__ co,
        const float* __restrict__ io,
        const float* __restrict__ w1, const float* __restrict__ b1,
        const float* __restrict__ w2, const float* __restrict__ b2,
        short* __restrict__ TC, short* __restrict__ O,
        const int* __restrict__ g1, const int* __restrict__ g2,
        int* __restrict__ cnt) {
    if (blockIdx.x >= MLPB) {                // ---- histogram part ----
        int gid = (blockIdx.x - MLPB) * 256 + threadIdx.x;
        if (gid < E1N) {
            int h = g1[gid];
            if (h < NVv) {
                int t = g1[E1N + gid];
                atomicAdd(cnt + (t >= NVv ? h : NVv + h), 1);
            }
        } else if (gid < E1N + E2N) {
            int h = g2[gid - E1N];
            if (h < NVv) atomicAdd(cnt + 2 * NVv + h, 1);
        }
        return;
    }

    // ---- MLP part ----
    __shared__ short wbuf[128][136];
    __shared__ short hbuf[64][136];
    const int tid = threadIdx.x;
    const int lane = tid & 63, wv = tid >> 6;
    const int n0b = blockIdx.x * 64;
    const int n0 = n0b + wv * 16;
    const int colw = lane & 15;              // col within a 16-tile
    const int k0 = (lane >> 4) * 8;          // k sub-offset for A/B frags

    // stage w1 -> bf16 LDS (row-major [j][k])
    for (int idx = tid * 4; idx < DD * DD; idx += 1024) {
        float4 v = *(const float4*)(w1 + idx);
        short* p = &wbuf[idx >> 7][idx & 127];
        p[0] = f2bf(v.x); p[1] = f2bf(v.y); p[2] = f2bf(v.z); p[3] = f2bf(v.w);
    }

    // A frags (layer 1) straight from global: row = n0 + (lane&15)
    int arow = n0 + colw; if (arow >= NNn) arow = NNn - 1;
    const float* ar = node_row(vc, cc, ic, arow);
    short8v a[4];
    #pragma unroll
    for (int kf = 0; kf < 4; ++kf) {
        const float* p = ar + kf * 32 + k0;
        float4 x = *(const float4*)p;
        float4 y = *(const float4*)(p + 4);
        short8v t;
        t[0] = f2bf(x.x); t[1] = f2bf(x.y); t[2] = f2bf(x.z); t[3] = f2bf(x.w);
        t[4] = f2bf(y.x); t[5] = f2bf(y.y); t[6] = f2bf(y.z); t[7] = f2bf(y.w);
        a[kf] = t;
    }
    __syncthreads();

    // layer 1: h = relu(A @ W1^T + b1) -> hbuf
    #pragma unroll
    for (int jt = 0; jt < 8; ++jt) {
        int j = jt * 16 + colw;
        float bb = b1[j];
        f32x4 acc = {bb, bb, bb, bb};
        #pragma unroll
        for (int kf = 0; kf < 4; ++kf) {
            short8v b = *(short8v*)&wbuf[j][kf * 32 + k0];
            acc = __builtin_amdgcn_mfma_f32_16x16x32_bf16(a[kf], b, acc, 0, 0, 0);
        }
        #pragma unroll
        for (int r = 0; r < 4; ++r)
            hbuf[wv * 16 + (lane >> 4) * 4 + r][j] = f2bf(fmaxf(acc[r], 0.f));
    }
    __syncthreads();                         // all waves done reading wbuf(w1)

    // A frags (layer 2) from own hbuf rows
    short8v a2[4];
    #pragma unroll
    for (int kf = 0; kf < 4; ++kf)
        a2[kf] = *(short8v*)&hbuf[wv * 16 + colw][kf * 32 + k0];

    // stage w2 over wbuf
    for (int idx = tid * 4; idx < DD * DD; idx += 1024) {
        float4 v = *(const float4*)(w2 + idx);
        short* p = &wbuf[idx >> 7][idx & 127];
        p[0] = f2bf(v.x); p[1] = f2bf(v.y); p[2] = f2bf(v.z); p[3] = f2bf(v.w);
    }
    __syncthreads();

    // layer 2 + exp -> hbuf as bf16 (hbuf A-frags already consumed)
    #pragma unroll
    for (int jt = 0; jt < 8; ++jt) {
        int j = jt * 16 + colw;
        float bb = b2[j];
        f32x4 acc = {bb, bb, bb, bb};
        #pragma unroll
        for (int kf = 0; kf < 4; ++kf) {
            short8v b = *(short8v*)&wbuf[j][kf * 32 + k0];
            acc = __builtin_amdgcn_mfma_f32_16x16x32_bf16(a2[kf], b, acc, 0, 0, 0);
        }
        #pragma unroll
        for (int r = 0; r < 4; ++r)
            hbuf[wv * 16 + (lane >> 4) * 4 + r][j] = f2bf(__expf(acc[r]));
    }
    __syncthreads();

    // TC build: 64 rows x 32 chunks = 2048 chunks / 256 threads = 8 iters
    #pragma unroll
    for (int i = 0; i < 8; ++i) {
        int cid = i * 256 + tid;
        int r = cid >> 5, p = cid & 31;
        int n = n0b + r;
        if (n >= NNn) continue;
        const float* cr = node_row(vc, cc, ic, n);
        float4 cv = *(const float4*)(cr + 4 * p);
        short4v el = *(const short4v*)&hbuf[r][4 * p];
        short8v s;
        s[0] = el.x; s[1] = el.y; s[2] = el.z; s[3] = el.w;
        s[4] = f2bf(cv.x); s[5] = f2bf(cv.y); s[6] = f2bf(cv.z); s[7] = f2bf(cv.w);
        *(short8v*)(TC + (size_t)n * 256 + 8 * p) = s;
    }
    // O build: 64 rows x 32 chunks of 8B
    #pragma unroll
    for (int i = 0; i < 8; ++i) {
        int cid = i * 256 + tid;
        int r = cid >> 5, l = cid & 31;
        int n = n0b + r;
        if (n >= NNn) continue;
        const float* orow = node_row(vo, co, io, n);
        float4 v = *(const float4*)(orow + 4 * l);
        short4v s;
        s.x = f2bf(v.x); s.y = f2bf(v.y); s.z = f2bf(v.z); s.w = f2bf(v.w);
        *(short4v*)(O + (size_t)n * 128 + 4 * l) = s;
    }
}

__global__ __launch_bounds__(1024) void scan_partial(const int* __restrict__ cnt,
                                                     int* __restrict__ bsum) {
    __shared__ int ws[16];
    int tid = threadIdx.x, lane = tid & 63, wvi = tid >> 6;
    int i = blockIdx.x * 1024 + tid;
    int v = (i < SCAN_N) ? cnt[i] : 0;
    #pragma unroll
    for (int off = 32; off; off >>= 1) v += __shfl_xor(v, off);
    if (lane == 0) ws[wvi] = v;
    __syncthreads();
    if (tid == 0) {
        int s = 0;
        #pragma unroll
        for (int w = 0; w < 16; ++w) s += ws[w];
        bsum[blockIdx.x] = s;
    }
}

// Final scan; block offset = reduce(bsum[0..blockIdx)) computed in-kernel.
__global__ __launch_bounds__(1024) void scan_final(const int* __restrict__ cnt,
                                                   const int* __restrict__ bsum,
                                                   int* __restrict__ base,
                                                   int* __restrict__ cur) {
    __shared__ int ws[16];
    __shared__ int s_off;
    int tid = threadIdx.x, lane = tid & 63, wvi = tid >> 6;

    int pre = 0;
    for (int j = tid; j < (int)blockIdx.x; j += 1024) pre += bsum[j];
    #pragma unroll
    for (int off = 32; off; off >>= 1) pre += __shfl_xor(pre, off);
    if (lane == 0) ws[wvi] = pre;
    __syncthreads();
    if (tid == 0) {
        int s = 0;
        #pragma unroll
        for (int w = 0; w < 16; ++w) s += ws[w];
        s_off = s;
    }
    __syncthreads();
    int boff = s_off;
    __syncthreads();                         // ws reuse below

    int i = blockIdx.x * 1024 + tid;
    int v = (i < SCAN_N) ? cnt[i] : 0;
    int incl = v;
    #pragma unroll
    for (int off = 1; off < 64; off <<= 1) {
        int o = __shfl_up(incl, off);
        if (lane >= off) incl += o;
    }
    if (lane == 63) ws[wvi] = incl;
    __syncthreads();
    int wpre = 0;
    for (int w = 0; w < wvi; ++w) wpre += ws[w];
    int excl = boff + wpre + incl - v;
    if (i < SCAN_N) { base[i] = excl; cur[i] = excl; }
    if (i == SCAN_N - 1) base[SCAN_N] = excl + v;   // grand total
}

__global__ void scatter(const int* __restrict__ g1, const int* __restrict__ g2,
                        int* __restrict__ cur, unsigned short* __restrict__ csr) {
    int gid = blockIdx.x * blockDim.x + threadIdx.x;
    if (gid < E1N) {
        int h = g1[gid];
        if (h < NVv) {
            int t = g1[E1N + gid];
            int sec = t >= NVv ? h : NVv + h;
            csr[atomicAdd(cur + sec, 1)] = (unsigned short)t;
        }
    } else if (gid < E1N + E2N) {
        int e = gid - E1N;
        int h = g2[e];
        if (h < NVv)
            csr[atomicAdd(cur + 2 * NVv + h, 1)] = (unsigned short)g2[E2N + e];
    }
}

__device__ __forceinline__ void acc8(short8v a, float d[4], float n[4]) {
    #pragma unroll
    for (int j = 0; j < 4; ++j) {
        float w = bf2f(a[j]);
        d[j] += w;
        n[j] = fmaf(w, bf2f(a[4 + j]), n[j]);
    }
}
__device__ __forceinline__ void acc4(short4v o, float m[4]) {
    m[0] = fmaxf(m[0], bf2f(o.x));
    m[1] = fmaxf(m[1], bf2f(o.y));
    m[2] = fmaxf(m[2], bf2f(o.z));
    m[3] = fmaxf(m[3], bf2f(o.w));
}

// One wave per segment, 2 edges per gather instruction: lanes 0-31 process
// even edges, lanes 32-63 odd edges (16B TC / 8B O per lane covers a full
// row across 32 lanes). Odd tails read the memset-zero dummy row NNn.
// Halves combined via shfl_xor(32) at the end.
__global__ void seg_fused(const int* __restrict__ base,
                          const unsigned short* __restrict__ csr,
                          const short* __restrict__ TC, const short* __restrict__ O,
                          float* __restrict__ out0, float* __restrict__ out1) {
    int seg = __builtin_amdgcn_readfirstlane(
        blockIdx.x * (blockDim.x >> 6) + (threadIdx.x >> 6));
    if (seg >= NVv) return;
    int lane = threadIdx.x & 63;
    int half = lane >> 5, q = lane & 31;
    float d[4] = {0.f, 0.f, 0.f, 0.f};
    float n[4] = {0.f, 0.f, 0.f, 0.f};
    float m[4] = {0.f, 0.f, 0.f, 0.f};       // 0 == relu floor + empty default

    // ---- g1 & t>=NV: softmax + offset max ----
    int s = base[seg], e = base[seg + 1];
    for (int c = s; c < e; c += 64) {
        int lim = e - c; if (lim > 64) lim = 64;
        int tl = (lane < lim) ? (int)csr[c + lane] : NNn;
        int k = 0;
        for (; k + 8 <= lim; k += 8) {
            short8v a[4]; short4v o[4];
            #pragma unroll
            for (int u = 0; u < 4; ++u) {
                int t = __shfl(tl, k + 2 * u + half);
                a[u] = *(const short8v*)(TC + ((size_t)t << 8) + 8 * q);
                o[u] = *(const short4v*)(O + ((size_t)t << 7) + 4 * q);
            }
            #pragma unroll
            for (int u = 0; u < 4; ++u) { acc8(a[u], d, n); acc4(o[u], m); }
        }
        for (; k < lim; k += 2) {
            int t = __shfl(tl, k + half);
            short8v a = *(const short8v*)(TC + ((size_t)t << 8) + 8 * q);
            short4v o = *(const short4v*)(O + ((size_t)t << 7) + 4 * q);
            acc8(a, d, n); acc4(o, m);
        }
    }

    // ---- g1 & t<NV: softmax only ----
    s = base[NVv + seg]; e = base[NVv + seg + 1];
    for (int c = s; c < e; c += 64) {
        int lim = e - c; if (lim > 64) lim = 64;
        int tl = (lane < lim) ? (int)csr[c + lane] : NNn;
        int k = 0;
        for (; k + 8 <= lim; k += 8) {
            short8v a[4];
            #pragma unroll
            for (int u = 0; u < 4; ++u) {
                int t = __shfl(tl, k + 2 * u + half);
                a[u] = *(const short8v*)(TC + ((size_t)t << 8) + 8 * q);
            }
            #pragma unroll
            for (int u = 0; u < 4; ++u) acc8(a[u], d, n);
        }
        for (; k < lim; k += 2) {
            int t = __shfl(tl, k + half);
            short8v a = *(const short8v*)(TC + ((size_t)t << 8) + 8 * q);
            acc8(a, d, n);
        }
    }

    // ---- g2: offset max only ----
    s = base[2 * NVv + seg]; e = base[2 * NVv + seg + 1];
    for (int c = s; c < e; c += 64) {
        int lim = e - c; if (lim > 64) lim = 64;
        int tl = (lane < lim) ? (int)csr[c + lane] : NNn;
        int k = 0;
        for (; k + 8 <= lim; k += 8) {
            short4v o[4];
            #pragma unroll
            for (int u = 0; u < 4; ++u) {
                int t = __shfl(tl, k + 2 * u + half);
                o[u] = *(const short4v*)(O + ((size_t)t << 7) + 4 * q);
            }
            #pragma unroll
            for (int u = 0; u < 4; ++u) acc4(o[u], m);
        }
        for (; k < lim; k += 2) {
            int t = __shfl(tl, k + half);
            short4v o = *(const short4v*)(O + ((size_t)t << 7) + 4 * q);
            acc4(o, m);
        }
    }

    // combine the two 32-lane halves
    #pragma unroll
    for (int j = 0; j < 4; ++j) {
        d[j] += __shfl_xor(d[j], 32);
        n[j] += __shfl_xor(n[j], 32);
        m[j] = fmaxf(m[j], __shfl_xor(m[j], 32));
    }
    float v[4], ss = 0.f;
    #pragma unroll
    for (int j = 0; j < 4; ++j) {
        v[j] = d[j] > 0.f ? n[j] / d[j] : 0.f;
        ss += v[j] * v[j];
    }
    #pragma unroll
    for (int off = 16; off; off >>= 1) ss += __shfl_xor(ss, off);
    float inv = 1.f / fmaxf(sqrtf(ss), 1e-12f);
    size_t b = (size_t)seg * DD + 4 * q;
    if (half == 0)
        *(float4*)(out0 + b) = make_float4(v[0]*inv, v[1]*inv, v[2]*inv, v[3]*inv);
    else
        *(float4*)(out1 + b) = make_float4(m[0], m[1], m[2], m[3]);
}

extern "C" void kernel_launch(void* const* d_in, const int* in_sizes, int n_in,
                              void* d_out, int out_size, void* d_ws, size_t ws_size,
                              hipStream_t stream) {
    const float* vc  = (const float*)d_in[0];
    const float* vo  = (const float*)d_in[1];
    const float* cc  = (const float*)d_in[2];
    const float* co  = (const float*)d_in[3];
    const float* ic  = (const float*)d_in[4];
    const float* io  = (const float*)d_in[5];
    // d_in[6] visit_time, d_in[11..14] time-net params: dead (lam == 1.0)
    const float* aw1 = (const float*)d_in[7];
    const float* ab1 = (const float*)d_in[8];
    const float* aw2 = (const float*)d_in[9];
    const float* ab2 = (const float*)d_in[10];
    const int*   g1  = (const int*)d_in[15];
    const int*   g2  = (const int*)d_in[16];

    float* out0 = (float*)d_out;                    // [NV,128] final emb
    float* out1 = out0 + (size_t)NVv * DD;          // [NV,128] final offset

    short* TC  = (short*)d_ws;                      // [NN+1,256] bf16 tables
    short* O   = TC + (size_t)(NNn + 1) * 256;      // [NN+1,128] bf16 offsets
    int* cnt   = (int*)(O + (size_t)(NNn + 1) * 128);  // SCAN_N
    int* base  = cnt + SCAN_N;                      // SCAN_N + 1
    int* cur   = base + SCAN_N + 1;                 // SCAN_N
    int* bsum  = cur + SCAN_N;                      // 128
    unsigned short* csr = (unsigned short*)(bsum + 128);   // <= E1N + E2N

    hipMemsetAsync(cnt, 0, SCAN_N * sizeof(int), stream);
    hipMemsetAsync(TC + (size_t)NNn * 256, 0, 512, stream);   // dummy row (sum-neutral)
    hipMemsetAsync(O + (size_t)NNn * 128, 0, 256, stream);    // dummy row (max-neutral)

    mlp_hist<<<MLPB + EBLK, 256, 0, stream>>>(vc, cc, ic, vo, co, io,
                                              aw1, ab1, aw2, ab2, TC, O,
                                              g1, g2, cnt);

    scan_partial<<<SCAN_NB, 1024, 0, stream>>>(cnt, bsum);
    scan_final<<<SCAN_NB, 1024, 0, stream>>>(cnt, bsum, base, cur);
    scatter<<<(E1N + E2N + 255) / 256, 256, 0, stream>>>(g1, g2, cur, csr);

    seg_fused<<<(NVv + 3) / 4, 256, 0, stream>>>(base, csr, TC, O, out0, out1);
}